// Round 18
// baseline (1011.198 us; speedup 1.0000x reference)
//
#include <hip/hip_runtime.h>
#include <math.h>

#define NN 16384
#define KNB 30
#define NE (NN*KNB)   // 491520

typedef __attribute__((ext_vector_type(8))) __bf16 bf16x8;
typedef __attribute__((ext_vector_type(4))) float f32x4;
typedef unsigned short ushortT;
typedef __attribute__((ext_vector_type(8))) unsigned short ushort8v;

#define SWZ(r) (((r)&7)<<4)

__device__ __forceinline__ ushortT f2bf(float x){
  __bf16 b = (__bf16)x;
  union { __bf16 b; ushortT u; } v; v.b = b; return v.u;
}
__device__ __forceinline__ float bf2f(ushortT u){
  union { unsigned int u32; float f; } v; v.u32 = ((unsigned int)u) << 16;
  return v.f;
}
__device__ __forceinline__ float bf2f_lo(unsigned int w){
  union { unsigned int u32; float f; } v; v.u32 = w << 16; return v.f;
}
__device__ __forceinline__ float bf2f_hi(unsigned int w){
  union { unsigned int u32; float f; } v; v.u32 = w & 0xffff0000u; return v.f;
}
// A&S 7.1.25 erf (3-term, |err| <= 2.5e-5) — ~100x below bf16 quantization of
// the stored activation; exact-GELU compatible at harness tolerance.
__device__ __forceinline__ float gelu_f(float x){
  float ax = fabsf(x) * 0.7071067811865476f;
  float t = 1.0f / (1.0f + 0.47047f * ax);
  float poly = t*(0.3480242f + t*(-0.0958798f + t*0.7478556f));
  float er = 1.0f - poly * __expf(-ax*ax);
  er = copysignf(er, x);
  return 0.5f * x * (1.0f + er);
}

// ---------------- merged prep kernel (r13/r17 form, unchanged) ----------------
// blocks 0..2047      : uwvh  (U = h@aw1[0:128] -> hh; WVhP att/node-interleaved)
// blocks 2048..2106   : pack  (WF1/WF2 fragments, plain col layout + bias1/2)
// blocks 2107..2235   : M = nw3@thw, c3 = nb3@thw
// WVhP layout: [node][256] bf16 where ushort 2c = att col c, 2c+1 = node col c.
__global__ void prep_kernel(const float* __restrict__ h,
                            const float* __restrict__ aw1, const float* __restrict__ nw1,
                            const float* __restrict__ aw2, const float* __restrict__ nw2,
                            const float* __restrict__ nw3, const float* __restrict__ nb3,
                            const float* __restrict__ thw,
                            const float* __restrict__ ab1, const float* __restrict__ nb1,
                            const float* __restrict__ ab2, const float* __restrict__ nb2,
                            ushortT* __restrict__ WF1, ushortT* __restrict__ WF2,
                            float* __restrict__ bias1, float* __restrict__ bias2,
                            float* __restrict__ U, ushortT* __restrict__ WVhP,
                            float* __restrict__ M, float* __restrict__ c3)
{
  __shared__ float sbuf[8*128];
  int tid = threadIdx.x;
  int b = blockIdx.x;

  if (b < 2048) {
    // ---- uwvh: 8 nodes, 384 threads ----
    size_t n0 = (size_t)b * 8;
    if (tid < 256) {
      int r = tid >> 5, c = (tid & 31) * 4;
      *(float4*)&sbuf[r*128 + c] = *(const float4*)(h + (n0 + r)*128 + c);
    }
    __syncthreads();
    int d = tid & 127, seg = tid >> 7;   // 0: U, 1: WVh att, 2: WVh node
    const float* wbase = (seg == 0) ? (aw1 + d)
                       : (seg == 1) ? (aw1 + 256*128 + d)
                                    : (nw1 + 128*128 + d);
    float s[8] = {0.f,0.f,0.f,0.f,0.f,0.f,0.f,0.f};
    for (int c = 0; c < 128; ++c) {
      float w = wbase[(size_t)c*128];
      #pragma unroll
      for (int r = 0; r < 8; ++r) s[r] += sbuf[r*128 + c] * w;
    }
    if (seg == 0) {
      #pragma unroll
      for (int r = 0; r < 8; ++r) U[(n0 + r)*128 + d] = s[r];
    } else {
      int off = seg - 1;                 // 0: att slot, 1: node slot
      #pragma unroll
      for (int r = 0; r < 8; ++r) WVhP[(n0 + r)*256 + 2*d + off] = f2bf(s[r]);
    }
    return;
  }
  if (b < 2107) {
    // ---- pack: u in [0, 59*256) over 256-thread slices ----
    if (tid >= 256) return;
    int u = (b - 2048) * 256 + tid;
    if (u < 8192) {
      int lane = u & 63, tile = u >> 6;
      int half = tile >> 6, nt = (tile >> 3) & 7, kt = tile & 7;
      int mrow = lane & 15, krow = lane >> 4;
      int n = half*128 + nt*16 + mrow, k0 = kt*32 + krow*8;
      ushort8v o;
      #pragma unroll
      for (int j = 0; j < 8; ++j) {
        int k = k0 + j;
        float v = (half == 0) ? aw1[(128 + k)*128 + n] : nw1[k*128 + (n - 128)];
        o[j] = f2bf(v);
      }
      *(ushort8v*)(WF1 + (size_t)u*8) = o;
      return;
    }
    u -= 8192;
    if (u < 4096) {
      int lane = u & 63, tile = u >> 6;
      int half = tile >> 5, nt = (tile >> 2) & 7, kt = tile & 3;
      int mrow = lane & 15, krow = lane >> 4;
      int n = half*128 + nt*16 + mrow, k0 = kt*32 + krow*8;
      ushort8v o;
      #pragma unroll
      for (int j = 0; j < 8; ++j) {
        int k = k0 + j;
        float v = (half == 0) ? aw2[k*128 + n] : nw2[k*128 + (n - 128)];
        o[j] = f2bf(v);
      }
      *(ushort8v*)(WF2 + (size_t)u*8) = o;
      return;
    }
    u -= 4096;
    if (u < 256) { bias1[u] = (u < 128) ? ab1[u] : nb1[u - 128]; return; }
    u -= 256;
    if (u < 256) { bias2[u] = (u < 128) ? ab2[u] : nb2[u - 128]; return; }
    return;
  }
  {
    // ---- M / c3: 129 blocks, 128 threads ----
    if (tid >= 128) return;
    int bb = b - 2107;
    int d = tid;
    sbuf[d] = (bb < 128) ? nw3[bb*128 + d] : nb3[d];
    __syncthreads();
    float s = 0.f;
    for (int n = 0; n < 128; ++n) s += sbuf[n] * thw[n*128 + d];
    if (bb < 128) M[bb*128 + d] = s;
    else c3[d] = s;
  }
}

// ---------------- persistent edge pipeline: 8 nodes/block, ping-pong LDS ------
// Per node (r13 wave decomposition: wave = 32 rows x (16 att + 16 node) cols,
// acc[2][2]): X(staged e) -G1-> Y(W1V1) -G2-> ep2 writes V2 into X -PV->.
// Y is dead after G2, so node n+1's e is LOADED during G2 (8 f32 regs) and
// WRITTEN to Y during PV — staging round-trip leaves the critical path.
// U read per-thread directly (no Ubs LDS). 3 barriers/node.
// LDS: buf[2][32][512B] + lgp[8][32] = 33792 B -> 4 blocks/CU (wave cap).
__global__ __launch_bounds__(512, 8) void edge_kernel(
    const float* __restrict__ e,
    const int* __restrict__ edge_idx,
    const ushortT* __restrict__ WVhP,
    const ushortT* __restrict__ WF1, const ushortT* __restrict__ WF2,
    const float* __restrict__ bias1, const float* __restrict__ bias2,
    const float* __restrict__ aw3, const float* __restrict__ ab3,
    float* __restrict__ hh)
{
  extern __shared__ char smem[];
  float* lgp = (float*)(smem + 32768);     // [8][32] logits partials

  const int tid  = threadIdx.x;
  const int lane = tid & 63;
  const int wid  = tid >> 6;
  const int mrow = lane & 15, krow = lane >> 4;
  const int ca = wid*16 + mrow;            // this thread's att col (0..127)
  const int sr = tid >> 4, sc8 = tid & 15; // staging slot: row, 16B-group
  const int n0 = blockIdx.x * 8;

  // per-thread column constants; aw3 pre-scaled by 1/sqrt(DH)
  const float b1a = bias1[ca],       b1n = bias1[128 + ca];
  const float b2a = bias2[ca],       b2n = bias2[128 + ca];
  const float aw3c = aw3[ca] * 0.08838834764831845f;

  // ---- prologue: stage e for node n0 into buf0 (synchronous, once) ----
  {
    ushort8v u = {0,0,0,0,0,0,0,0};
    if (sr < KNB) {
      const float* src = e + ((size_t)n0*KNB + sr)*128 + sc8*8;
      float4 v0 = *(const float4*)src;
      float4 v1 = *(const float4*)(src + 4);
      u[0]=f2bf(v0.x); u[1]=f2bf(v0.y); u[2]=f2bf(v0.z); u[3]=f2bf(v0.w);
      u[4]=f2bf(v1.x); u[5]=f2bf(v1.y); u[6]=f2bf(v1.z); u[7]=f2bf(v1.w);
    }
    *(ushort8v*)(smem + sr*512 + ((sc8*16) ^ SWZ(sr))) = u;
  }
  __syncthreads();

  for (int it = 0; it < 8; ++it) {
    const int node = n0 + it;
    const long e0 = (long)node * KNB;
    char* Xc = smem + ((it & 1) ? 16384 : 0);
    char* Yc = smem + ((it & 1) ? 0 : 16384);

    // U (direct per-thread) + WVh gathers — issued now, consumed in ep1,
    // latency overlaps GEMM1.
    float uu = hh[(size_t)node*128 + ca];
    unsigned int wv[8];
    #pragma unroll
    for (int g = 0; g < 8; ++g) {
      int row_ = (g >> 2)*16 + krow*4 + (g & 3);
      wv[g] = 0u;
      if (row_ < KNB) {
        int dst = edge_idx[NE + e0 + row_];
        wv[g] = ((const unsigned int*)(WVhP + (size_t)dst*256))[ca];
      }
    }

    f32x4 acc[2][2];
    #pragma unroll
    for (int mt = 0; mt < 2; ++mt)
      #pragma unroll
      for (int j = 0; j < 2; ++j) acc[mt][j] = (f32x4){0.f,0.f,0.f,0.f};

    // ---- GEMM1: e[32x128] @ WF1 (A from Xc) ----
    #pragma unroll
    for (int kt = 0; kt < 4; ++kt) {
      int koff = kt*64 + krow*16;
      bf16x8 a0 = *(const bf16x8*)(Xc + mrow*512 + (koff ^ SWZ(mrow)));
      bf16x8 a1 = *(const bf16x8*)(Xc + (16 + mrow)*512 + (koff ^ SWZ(16 + mrow)));
      bf16x8 ba = *(const bf16x8*)(WF1 + ((size_t)(wid*8 + kt))*512 + lane*8);
      bf16x8 bn = *(const bf16x8*)(WF1 + ((size_t)((8 + wid)*8 + kt))*512 + lane*8);
      acc[0][0] = __builtin_amdgcn_mfma_f32_16x16x32_bf16(a0, ba, acc[0][0], 0, 0, 0);
      acc[1][0] = __builtin_amdgcn_mfma_f32_16x16x32_bf16(a1, ba, acc[1][0], 0, 0, 0);
      acc[0][1] = __builtin_amdgcn_mfma_f32_16x16x32_bf16(a0, bn, acc[0][1], 0, 0, 0);
      acc[1][1] = __builtin_amdgcn_mfma_f32_16x16x32_bf16(a1, bn, acc[1][1], 0, 0, 0);
    }

    // epilogue 1 (no barrier: acc wave-private, output -> Yc)
    {
      const float b1u = b1a + uu;
      #pragma unroll
      for (int mt = 0; mt < 2; ++mt)
        #pragma unroll
        for (int rr = 0; rr < 4; ++rr) {
          int row_ = mt*16 + krow*4 + rr;
          int g = mt*4 + rr;
          char* yrow = Yc + row_*512;
          int sw = SWZ(row_);
          float x = fmaxf(acc[mt][0][rr] + b1u + bf2f_lo(wv[g]), 0.f);
          *(ushortT*)(yrow + ((2*ca) ^ sw)) = f2bf(x);
          float y = gelu_f(acc[mt][1][rr] + b1n + bf2f_hi(wv[g]));
          *(ushortT*)(yrow + ((256 + 2*ca) ^ sw)) = f2bf(y);
        }
    }
    __syncthreads();   // barrier 1: Yc (W1|V1) visible to all waves

    // issue next node's e loads now — latency hides under GEMM2 + ep2
    float enx[8];
    if (it < 7 && sr < KNB) {
      const float* src = e + ((size_t)(node + 1)*KNB + sr)*128 + sc8*8;
      float4 v0 = *(const float4*)src;
      float4 v1 = *(const float4*)(src + 4);
      enx[0]=v0.x; enx[1]=v0.y; enx[2]=v0.z; enx[3]=v0.w;
      enx[4]=v1.x; enx[5]=v1.y; enx[6]=v1.z; enx[7]=v1.w;
    }

    // ---- GEMM2: W2 = W1@aw2 (att), V2pre = V1@nw2 (node), A from Yc ----
    #pragma unroll
    for (int mt = 0; mt < 2; ++mt)
      #pragma unroll
      for (int j = 0; j < 2; ++j) acc[mt][j] = (f32x4){0.f,0.f,0.f,0.f};
    #pragma unroll
    for (int kt = 0; kt < 4; ++kt) {
      int koff = kt*64 + krow*16;
      bf16x8 aw0 = *(const bf16x8*)(Yc + mrow*512 + (koff ^ SWZ(mrow)));
      bf16x8 aw1v = *(const bf16x8*)(Yc + (16 + mrow)*512 + (koff ^ SWZ(16 + mrow)));
      bf16x8 av0 = *(const bf16x8*)(Yc + mrow*512 + ((256 + koff) ^ SWZ(mrow)));
      bf16x8 av1 = *(const bf16x8*)(Yc + (16 + mrow)*512 + ((256 + koff) ^ SWZ(16 + mrow)));
      bf16x8 ba = *(const bf16x8*)(WF2 + ((size_t)(wid*4 + kt))*512 + lane*8);
      bf16x8 bn = *(const bf16x8*)(WF2 + ((size_t)((8 + wid)*4 + kt))*512 + lane*8);
      acc[0][0] = __builtin_amdgcn_mfma_f32_16x16x32_bf16(aw0, ba, acc[0][0], 0, 0, 0);
      acc[1][0] = __builtin_amdgcn_mfma_f32_16x16x32_bf16(aw1v, ba, acc[1][0], 0, 0, 0);
      acc[0][1] = __builtin_amdgcn_mfma_f32_16x16x32_bf16(av0, bn, acc[0][1], 0, 0, 0);
      acc[1][1] = __builtin_amdgcn_mfma_f32_16x16x32_bf16(av1, bn, acc[1][1], 0, 0, 0);
    }

    // epilogue 2 (no barrier): logits partial from in-reg W2, V2 -> Xc left half
    {
      #pragma unroll
      for (int mt = 0; mt < 2; ++mt)
        #pragma unroll
        for (int rr = 0; rr < 4; ++rr) {
          int row_ = mt*16 + krow*4 + rr;
          int sw = SWZ(row_);
          float lsum = fmaxf(acc[mt][0][rr] + b2a, 0.f) * aw3c;
          lsum += __shfl_xor(lsum, 1);
          lsum += __shfl_xor(lsum, 2);
          lsum += __shfl_xor(lsum, 4);
          lsum += __shfl_xor(lsum, 8);
          if (mrow == 0) lgp[wid*32 + row_] = lsum;
          float y = gelu_f(acc[mt][1][rr] + b2n);
          *(ushortT*)(Xc + row_*512 + ((2*ca) ^ sw)) = f2bf(y);
        }
    }
    __syncthreads();   // barrier 2: V2 (Xc) + lgp visible; Yc now dead

    // ---- PV phase: softmax + q = att@V2 (reads Xc) ∥ stage next-e -> Yc ----
    if (it < 7) {
      ushort8v u = {0,0,0,0,0,0,0,0};
      if (sr < KNB) {
        u[0]=f2bf(enx[0]); u[1]=f2bf(enx[1]); u[2]=f2bf(enx[2]); u[3]=f2bf(enx[3]);
        u[4]=f2bf(enx[4]); u[5]=f2bf(enx[5]); u[6]=f2bf(enx[6]); u[7]=f2bf(enx[7]);
      }
      *(ushort8v*)(Yc + sr*512 + ((sc8*16) ^ SWZ(sr))) = u;
    }
    {
      float x = -INFINITY;
      if (lane < KNB) {
        x = lgp[lane];
        #pragma unroll
        for (int w = 1; w < 8; ++w) x += lgp[w*32 + lane];
      }
      float m = x;
      #pragma unroll
      for (int off = 16; off >= 1; off >>= 1) m = fmaxf(m, __shfl_xor(m, off));
      float p = (lane < KNB) ? __expf(x - m) : 0.f;
      float ssum = p;
      #pragma unroll
      for (int off = 16; off >= 1; off >>= 1) ssum += __shfl_xor(ssum, off);
      float attv = p / ssum;   // lanes 30,31 -> 0 (rows 30/31 finite, weight 0)

      int pr = lane & 7, ks = lane >> 3;
      int col0 = wid*16 + pr*2;
      float s0 = 0.f, s1 = 0.f;
      #pragma unroll
      for (int j = 0; j < 4; ++j) {
        int k2 = ks + 8*j;                // 0..31; attv[30],attv[31] == 0
        float a = __shfl(attv, k2);
        unsigned int w = *(const unsigned int*)(Xc + k2*512 + ((2*col0) ^ SWZ(k2)));
        s0 += a * bf2f_lo(w);
        s1 += a * bf2f_hi(w);
      }
      s0 += __shfl_xor(s0, 8);  s1 += __shfl_xor(s1, 8);
      s0 += __shfl_xor(s0, 16); s1 += __shfl_xor(s1, 16);
      s0 += __shfl_xor(s0, 32); s1 += __shfl_xor(s1, 32);
      if (lane < 8) {
        float2 o; o.x = s0; o.y = s1;
        *(float2*)(hh + (size_t)node*128 + col0) = o;
      }
    }
    __syncthreads();   // barrier 3: staged Yc ready; Xc free for next ep1
  }
}

// ---------------- deterministic column reduction over nodes (on q) ------------
__global__ void reduce1_kernel(const float* __restrict__ hh, float* __restrict__ p2) {
  int b = blockIdx.x, tid = threadIdx.x;
  int d = tid & 127, half = tid >> 7;
  float s = 0.f;
  const float* base = hh + (size_t)(b*64 + half*32)*128 + d;
  #pragma unroll 4
  for (int i = 0; i < 32; ++i) s += base[(size_t)i*128];
  __shared__ float ps[256];
  ps[tid] = s; __syncthreads();
  if (tid < 128) p2[b*128 + tid] = ps[tid] + ps[tid + 128];
}

// gate: c = (mean q)@M + c3; g = sigmoid(MLP(c))
__global__ void gate_kernel(const float* __restrict__ p2,
                            const float* __restrict__ M, const float* __restrict__ c3,
                            const float* __restrict__ gw1, const float* __restrict__ gb1,
                            const float* __restrict__ gw2, const float* __restrict__ gb2,
                            const float* __restrict__ gw3, const float* __restrict__ gb3,
                            float* __restrict__ gout) {
  int tid = threadIdx.x;
  int d = tid & 127, half = tid >> 7;
  float s = 0.f;
  for (int i = 0; i < 128; ++i) s += p2[(half*128 + i)*128 + d];
  __shared__ float ps[256];
  __shared__ float cv[128], cv2[128], y1[128], y2[128];
  ps[tid] = s; __syncthreads();
  if (tid < 128) cv[tid] = (ps[tid] + ps[tid+128]) * (1.f / (float)NN);
  __syncthreads();
  if (tid < 128) {
    float a = c3[tid];
    for (int c = 0; c < 128; ++c) a += cv[c] * M[c*128 + tid];
    cv2[tid] = a;
  }
  __syncthreads();
  if (tid < 128) {
    float a = gb1[tid];
    for (int c = 0; c < 128; ++c) a += cv2[c] * gw1[c*128 + tid];
    y1[tid] = fmaxf(a, 0.f);
  }
  __syncthreads();
  if (tid < 128) {
    float a = gb2[tid];
    for (int c = 0; c < 128; ++c) a += y1[c] * gw2[c*128 + tid];
    y2[tid] = fmaxf(a, 0.f);
  }
  __syncthreads();
  if (tid < 128) {
    float a = gb3[tid];
    for (int c = 0; c < 128; ++c) a += y2[c] * gw3[c*128 + tid];
    gout[tid] = 1.f / (1.f + __expf(-a));
  }
}

// ---------------- fused (V3 + to_h + gate): out = (q@M + c3)*g, in place ------
__global__ void toh_scale_kernel(float* __restrict__ hh, const float* __restrict__ M,
                                 const float* __restrict__ c3,
                                 const float* __restrict__ gv)
{
  __shared__ float hs[16][128];
  int tid = threadIdx.x;
  size_t n0 = (size_t)blockIdx.x * 16;
  {
    int r = tid >> 4, c = (tid & 15) * 8;
    const float* src = hh + (n0 + r)*128 + c;
    *(float4*)&hs[r][c]     = *(const float4*)src;
    *(float4*)&hs[r][c + 4] = *(const float4*)(src + 4);
  }
  __syncthreads();
  int d = tid & 127, gq = tid >> 7;
  float s[8] = {0.f,0.f,0.f,0.f,0.f,0.f,0.f,0.f};
  for (int c = 0; c < 128; ++c) {
    float w = M[c*128 + d];
    #pragma unroll
    for (int r = 0; r < 8; ++r) s[r] += hs[gq*8 + r][c] * w;
  }
  float gd = gv[d];
  float cd = c3[d];
  #pragma unroll
  for (int r = 0; r < 8; ++r) hh[(n0 + gq*8 + r)*128 + d] = (s[r] + cd) * gd;
}

extern "C" void kernel_launch(void* const* d_in, const int* in_sizes, int n_in,
                              void* d_out, int out_size, void* d_ws, size_t ws_size,
                              hipStream_t stream) {
  const float* h   = (const float*)d_in[0];
  const float* e   = (const float*)d_in[1];
  const float* aw1 = (const float*)d_in[2];
  const float* ab1 = (const float*)d_in[3];
  const float* aw2 = (const float*)d_in[4];
  const float* ab2 = (const float*)d_in[5];
  const float* aw3 = (const float*)d_in[6];
  const float* ab3 = (const float*)d_in[7];
  const float* nw1 = (const float*)d_in[8];
  const float* nb1 = (const float*)d_in[9];
  const float* nw2 = (const float*)d_in[10];
  const float* nb2 = (const float*)d_in[11];
  const float* nw3 = (const float*)d_in[12];
  const float* nb3 = (const float*)d_in[13];
  const float* thw = (const float*)d_in[14];
  const float* gw1 = (const float*)d_in[15];
  const float* gb1 = (const float*)d_in[16];
  const float* gw2 = (const float*)d_in[17];
  const float* gb2 = (const float*)d_in[18];
  const float* gw3 = (const float*)d_in[19];
  const float* gb3 = (const float*)d_in[20];
  const int* edge_idx = (const int*)d_in[21];

  char* ws = (char*)d_ws;
  ushortT* WF1 = (ushortT*)(ws + 0);        // 131072 B
  ushortT* WF2 = (ushortT*)(ws + 131072);   // 65536 B
  float* bias1 = (float*)(ws + 196608);     // 1024 B
  float* bias2 = (float*)(ws + 197632);     // 1024 B
  float* p2    = (float*)(ws + 198656);     // 131072 B
  float* gout  = (float*)(ws + 329728);     // 512 B
  float* Mw    = (float*)(ws + 330240);     // 65536 B
  float* c3w   = (float*)(ws + 395776);     // 512 B
  ushortT* WVhP= (ushortT*)(ws + 396288);   // 8388608 B
  float* hh    = (float*)d_out;

  // merged prep: uwvh (2048) + pack (59) + M (129)
  prep_kernel<<<2236, 384, 0, stream>>>(h, aw1, nw1, aw2, nw2, nw3, nb3, thw,
                                        ab1, nb1, ab2, nb2,
                                        WF1, WF2, bias1, bias2,
                                        hh, WVhP, Mw, c3w);

  const int SMEM = 33792;
  hipFuncSetAttribute((const void*)edge_kernel,
                      hipFuncAttributeMaxDynamicSharedMemorySize, SMEM);
  edge_kernel<<<NN/8, 512, SMEM, stream>>>(e, edge_idx, WVhP, WF1, WF2,
                                           bias1, bias2, aw3, ab3, hh);

  reduce1_kernel<<<256, 256, 0, stream>>>(hh, p2);
  gate_kernel<<<1, 256, 0, stream>>>(p2, Mw, c3w, gw1, gb1, gw2, gb2, gw3, gb3, gout);
  toh_scale_kernel<<<NN/16, 256, 0, stream>>>(hh, Mw, c3w, gout);
}

// Round 19
// 306.274 us; speedup vs baseline: 3.3016x; 3.3016x over previous
//
#include <hip/hip_runtime.h>
#include <math.h>

#define NN 16384
#define KNB 30
#define NE (NN*KNB)   // 491520

typedef __attribute__((ext_vector_type(8))) __bf16 bf16x8;
typedef __attribute__((ext_vector_type(4))) float f32x4;
typedef unsigned short ushortT;
typedef __attribute__((ext_vector_type(8))) unsigned short ushort8v;

#define SWZ(r) (((r)&7)<<4)

__device__ __forceinline__ ushortT f2bf(float x){
  __bf16 b = (__bf16)x;
  union { __bf16 b; ushortT u; } v; v.b = b; return v.u;
}
__device__ __forceinline__ float bf2f(ushortT u){
  union { unsigned int u32; float f; } v; v.u32 = ((unsigned int)u) << 16;
  return v.f;
}
__device__ __forceinline__ float bf2f_lo(unsigned int w){
  union { unsigned int u32; float f; } v; v.u32 = w << 16; return v.f;
}
__device__ __forceinline__ float bf2f_hi(unsigned int w){
  union { unsigned int u32; float f; } v; v.u32 = w & 0xffff0000u; return v.f;
}
// A&S 7.1.25 erf (3-term, |err| <= 2.5e-5) — ~100x below bf16 quantization of
// the stored activation; exact-GELU compatible at harness tolerance.
__device__ __forceinline__ float gelu_f(float x){
  float ax = fabsf(x) * 0.7071067811865476f;
  float t = 1.0f / (1.0f + 0.47047f * ax);
  float poly = t*(0.3480242f + t*(-0.0958798f + t*0.7478556f));
  float er = 1.0f - poly * __expf(-ax*ax);
  er = copysignf(er, x);
  return 0.5f * x * (1.0f + er);
}

// ---------------- merged prep kernel ------------------------------------------
// blocks 0..2047      : uwvh  (U = h@aw1[0:128] -> hh; WVhP att/node-interleaved)
// blocks 2048..2106   : pack  (WF1/WF2 fragments, plain col layout + bias1/2)
// blocks 2107..2235   : M = nw3@thw, c3 = nb3@thw
// WVhP layout: [node][256] bf16 where ushort 2c = att col c, 2c+1 = node col c.
__global__ void prep_kernel(const float* __restrict__ h,
                            const float* __restrict__ aw1, const float* __restrict__ nw1,
                            const float* __restrict__ aw2, const float* __restrict__ nw2,
                            const float* __restrict__ nw3, const float* __restrict__ nb3,
                            const float* __restrict__ thw,
                            const float* __restrict__ ab1, const float* __restrict__ nb1,
                            const float* __restrict__ ab2, const float* __restrict__ nb2,
                            ushortT* __restrict__ WF1, ushortT* __restrict__ WF2,
                            float* __restrict__ bias1, float* __restrict__ bias2,
                            float* __restrict__ U, ushortT* __restrict__ WVhP,
                            float* __restrict__ M, float* __restrict__ c3)
{
  __shared__ float sbuf[8*128];
  int tid = threadIdx.x;
  int b = blockIdx.x;

  if (b < 2048) {
    // ---- uwvh: 8 nodes, 384 threads ----
    size_t n0 = (size_t)b * 8;
    if (tid < 256) {
      int r = tid >> 5, c = (tid & 31) * 4;
      *(float4*)&sbuf[r*128 + c] = *(const float4*)(h + (n0 + r)*128 + c);
    }
    __syncthreads();
    int d = tid & 127, seg = tid >> 7;   // 0: U, 1: WVh att, 2: WVh node
    const float* wbase = (seg == 0) ? (aw1 + d)
                       : (seg == 1) ? (aw1 + 256*128 + d)
                                    : (nw1 + 128*128 + d);
    float s[8] = {0.f,0.f,0.f,0.f,0.f,0.f,0.f,0.f};
    for (int c = 0; c < 128; ++c) {
      float w = wbase[(size_t)c*128];
      #pragma unroll
      for (int r = 0; r < 8; ++r) s[r] += sbuf[r*128 + c] * w;
    }
    if (seg == 0) {
      #pragma unroll
      for (int r = 0; r < 8; ++r) U[(n0 + r)*128 + d] = s[r];
    } else {
      int off = seg - 1;                 // 0: att slot, 1: node slot
      #pragma unroll
      for (int r = 0; r < 8; ++r) WVhP[(n0 + r)*256 + 2*d + off] = f2bf(s[r]);
    }
    return;
  }
  if (b < 2107) {
    // ---- pack: u in [0, 59*256) over 256-thread slices ----
    if (tid >= 256) return;
    int u = (b - 2048) * 256 + tid;
    if (u < 8192) {
      int lane = u & 63, tile = u >> 6;
      int half = tile >> 6, nt = (tile >> 3) & 7, kt = tile & 7;
      int mrow = lane & 15, krow = lane >> 4;
      int n = half*128 + nt*16 + mrow, k0 = kt*32 + krow*8;
      ushort8v o;
      #pragma unroll
      for (int j = 0; j < 8; ++j) {
        int k = k0 + j;
        float v = (half == 0) ? aw1[(128 + k)*128 + n] : nw1[k*128 + (n - 128)];
        o[j] = f2bf(v);
      }
      *(ushort8v*)(WF1 + (size_t)u*8) = o;
      return;
    }
    u -= 8192;
    if (u < 4096) {
      int lane = u & 63, tile = u >> 6;
      int half = tile >> 5, nt = (tile >> 2) & 7, kt = tile & 3;
      int mrow = lane & 15, krow = lane >> 4;
      int n = half*128 + nt*16 + mrow, k0 = kt*32 + krow*8;
      ushort8v o;
      #pragma unroll
      for (int j = 0; j < 8; ++j) {
        int k = k0 + j;
        float v = (half == 0) ? aw2[k*128 + n] : nw2[k*128 + (n - 128)];
        o[j] = f2bf(v);
      }
      *(ushort8v*)(WF2 + (size_t)u*8) = o;
      return;
    }
    u -= 4096;
    if (u < 256) { bias1[u] = (u < 128) ? ab1[u] : nb1[u - 128]; return; }
    u -= 256;
    if (u < 256) { bias2[u] = (u < 128) ? ab2[u] : nb2[u - 128]; return; }
    return;
  }
  {
    // ---- M / c3: 129 blocks, 128 threads ----
    if (tid >= 128) return;
    int bb = b - 2107;
    int d = tid;
    sbuf[d] = (bb < 128) ? nw3[bb*128 + d] : nb3[d];
    __syncthreads();
    float s = 0.f;
    for (int n = 0; n < 128; ++n) s += sbuf[n] * thw[n*128 + d];
    if (bb < 128) M[bb*128 + d] = s;
    else c3[d] = s;
  }
}

// ---------------- fused edge pipeline: 1 node, 512 threads, 3 barriers --------
// Wave decomposition: each wave owns ALL 32 rows x (16 att + 16 node) cols
// -> acc[2][2] (16 AGPRs); per-wave B loads 8/GEMM, no wid-duplication:
// block B traffic 96KB. WVh gather: 1 interleaved dword (att|node) per row.
// LDS: Xb[32][512B] + Yb[32][512B] swz bf16; lgp[8][32]; Ubs[128]. 34304 B.
__global__ __launch_bounds__(512, 8) void edge_kernel(
    const float* __restrict__ e,
    const int* __restrict__ edge_idx,
    const ushortT* __restrict__ WVhP,
    const ushortT* __restrict__ WF1, const ushortT* __restrict__ WF2,
    const float* __restrict__ bias1, const float* __restrict__ bias2,
    const float* __restrict__ aw3, const float* __restrict__ ab3,
    float* __restrict__ hh)
{
  extern __shared__ char smem[];
  char*  Xb   = smem;                       // [32][512B] swizzled bf16 (16384 B)
  char*  Yb   = smem + 16384;               // [32][512B] swizzled bf16 (16384 B)
  float* lgp  = (float*)(smem + 32768);     // [8][32] logits partials
  float* Ubs  = (float*)(smem + 33792);     // [128]

  const int tid  = threadIdx.x;
  const int lane = tid & 63;
  const int wid  = tid >> 6;
  const int node = blockIdx.x;
  const long e0 = (long)node * KNB;

  const int mrow = lane & 15, krow = lane >> 4;
  const int ca = wid*16 + mrow;            // this thread's att col (0..127)

  // U value for this thread's column (precomputed into hh row)
  float uval = 0.f;
  if (tid < 128) uval = hh[(size_t)node*128 + tid];

  // ---- Phase 0a: stage e -> bf16 Xb cols 0..127; rows 30/31 zeroed ----
  {
    int r = tid >> 4, c8 = tid & 15;       // 32 rows x 16 groups = 512
    ushort8v u = {0,0,0,0,0,0,0,0};
    if (r < KNB) {
      const float* src = e + ((size_t)(e0 + r))*128 + c8*8;
      float4 v0 = *(const float4*)src;
      float4 v1 = *(const float4*)(src + 4);
      u[0]=f2bf(v0.x); u[1]=f2bf(v0.y); u[2]=f2bf(v0.z); u[3]=f2bf(v0.w);
      u[4]=f2bf(v1.x); u[5]=f2bf(v1.y); u[6]=f2bf(v1.z); u[7]=f2bf(v1.w);
    }
    *(ushort8v*)(Xb + r*512 + ((c8*16) ^ SWZ(r))) = u;
  }

  // ---- Phase 0b: issue WVh gathers — 1 interleaved dword per owned row ----
  unsigned int wv[8];
  #pragma unroll
  for (int g = 0; g < 8; ++g) {
    int row_ = (g >> 2)*16 + krow*4 + (g & 3);
    wv[g] = 0u;
    if (row_ < KNB) {
      int dst = edge_idx[NE + e0 + row_];
      wv[g] = ((const unsigned int*)(WVhP + (size_t)dst*256))[ca];
    }
  }
  if (tid < 128) Ubs[tid] = uval;
  // barrier 1: LDS drained; WVh gathers stay in flight through GEMM1
  asm volatile("s_waitcnt lgkmcnt(0)" ::: "memory");
  __builtin_amdgcn_s_barrier();

  // per-thread column constants; aw3 pre-scaled by 1/sqrt(DH)
  const float b1a = bias1[ca],       b1n = bias1[128 + ca];
  const float b2a = bias2[ca],       b2n = bias2[128 + ca];
  const float aw3c = aw3[ca] * 0.08838834764831845f;

  f32x4 acc[2][2];
  #pragma unroll
  for (int mt = 0; mt < 2; ++mt)
    #pragma unroll
    for (int j = 0; j < 2; ++j) acc[mt][j] = (f32x4){0.f,0.f,0.f,0.f};

  // ---- GEMM1: e[32x128] @ WF1 -> all 32 rows x (att tile wid, node tile wid) --
  #pragma unroll
  for (int kt = 0; kt < 4; ++kt) {
    int koff = kt*64 + krow*16;
    bf16x8 a0 = *(const bf16x8*)(Xb + mrow*512 + (koff ^ SWZ(mrow)));
    bf16x8 a1 = *(const bf16x8*)(Xb + (16 + mrow)*512 + (koff ^ SWZ(16 + mrow)));
    bf16x8 ba = *(const bf16x8*)(WF1 + ((size_t)(wid*8 + kt))*512 + lane*8);
    bf16x8 bn = *(const bf16x8*)(WF1 + ((size_t)((8 + wid)*8 + kt))*512 + lane*8);
    acc[0][0] = __builtin_amdgcn_mfma_f32_16x16x32_bf16(a0, ba, acc[0][0], 0, 0, 0);
    acc[1][0] = __builtin_amdgcn_mfma_f32_16x16x32_bf16(a1, ba, acc[1][0], 0, 0, 0);
    acc[0][1] = __builtin_amdgcn_mfma_f32_16x16x32_bf16(a0, bn, acc[0][1], 0, 0, 0);
    acc[1][1] = __builtin_amdgcn_mfma_f32_16x16x32_bf16(a1, bn, acc[1][1], 0, 0, 0);
  }

  // epilogue 1 (no barrier: acc wave-private, output -> Yb)
  {
    const float b1u = b1a + Ubs[ca];
    #pragma unroll
    for (int mt = 0; mt < 2; ++mt)
      #pragma unroll
      for (int rr = 0; rr < 4; ++rr) {
        int row_ = mt*16 + krow*4 + rr;
        int g = mt*4 + rr;
        char* yrow = Yb + row_*512;
        int sw = SWZ(row_);
        float x = fmaxf(acc[mt][0][rr] + b1u + bf2f_lo(wv[g]), 0.f);
        *(ushortT*)(yrow + ((2*ca) ^ sw)) = f2bf(x);
        float y = gelu_f(acc[mt][1][rr] + b1n + bf2f_hi(wv[g]));
        *(ushortT*)(yrow + ((256 + 2*ca) ^ sw)) = f2bf(y);
      }
  }
  __syncthreads();   // barrier 2: Yb (W1|V1) visible to all waves

  // ---- GEMM2: W2 = W1@aw2 (att), V2pre = V1@nw2 (node), A from Yb ----
  #pragma unroll
  for (int mt = 0; mt < 2; ++mt)
    #pragma unroll
    for (int j = 0; j < 2; ++j) acc[mt][j] = (f32x4){0.f,0.f,0.f,0.f};
  #pragma unroll
  for (int kt = 0; kt < 4; ++kt) {
    int koff = kt*64 + krow*16;
    bf16x8 aw0 = *(const bf16x8*)(Yb + mrow*512 + (koff ^ SWZ(mrow)));
    bf16x8 aw1v = *(const bf16x8*)(Yb + (16 + mrow)*512 + (koff ^ SWZ(16 + mrow)));
    bf16x8 av0 = *(const bf16x8*)(Yb + mrow*512 + ((256 + koff) ^ SWZ(mrow)));
    bf16x8 av1 = *(const bf16x8*)(Yb + (16 + mrow)*512 + ((256 + koff) ^ SWZ(16 + mrow)));
    bf16x8 ba = *(const bf16x8*)(WF2 + ((size_t)(wid*4 + kt))*512 + lane*8);
    bf16x8 bn = *(const bf16x8*)(WF2 + ((size_t)((8 + wid)*4 + kt))*512 + lane*8);
    acc[0][0] = __builtin_amdgcn_mfma_f32_16x16x32_bf16(aw0, ba, acc[0][0], 0, 0, 0);
    acc[1][0] = __builtin_amdgcn_mfma_f32_16x16x32_bf16(aw1v, ba, acc[1][0], 0, 0, 0);
    acc[0][1] = __builtin_amdgcn_mfma_f32_16x16x32_bf16(av0, bn, acc[0][1], 0, 0, 0);
    acc[1][1] = __builtin_amdgcn_mfma_f32_16x16x32_bf16(av1, bn, acc[1][1], 0, 0, 0);
  }

  // epilogue 2 (no barrier): logits partial from in-reg W2, V2 -> Xb left half
  {
    #pragma unroll
    for (int mt = 0; mt < 2; ++mt)
      #pragma unroll
      for (int rr = 0; rr < 4; ++rr) {
        int row_ = mt*16 + krow*4 + rr;
        int sw = SWZ(row_);
        float lsum = fmaxf(acc[mt][0][rr] + b2a, 0.f) * aw3c;
        lsum += __shfl_xor(lsum, 1);
        lsum += __shfl_xor(lsum, 2);
        lsum += __shfl_xor(lsum, 4);
        lsum += __shfl_xor(lsum, 8);
        if (mrow == 0) lgp[wid*32 + row_] = lsum;
        float y = gelu_f(acc[mt][1][rr] + b2n);
        *(ushortT*)(Xb + row_*512 + ((2*ca) ^ sw)) = f2bf(y);
      }
  }
  __syncthreads();   // barrier 3: V2 (Xb) + lgp visible

  // ---- softmax (shift-invariant, 32-lane reduce) + q = att@V2 (paired) ----
  {
    float x = -INFINITY;
    if (lane < KNB) {
      x = lgp[lane];
      #pragma unroll
      for (int w = 1; w < 8; ++w) x += lgp[w*32 + lane];
    }
    float m = x;
    #pragma unroll
    for (int off = 16; off >= 1; off >>= 1) m = fmaxf(m, __shfl_xor(m, off));
    float p = (lane < KNB) ? __expf(x - m) : 0.f;
    float ssum = p;
    #pragma unroll
    for (int off = 16; off >= 1; off >>= 1) ssum += __shfl_xor(ssum, off);
    float attv = p / ssum;   // lanes 30,31 -> 0 (rows 30/31 finite, weight 0)

    int pr = lane & 7, ks = lane >> 3;
    int col0 = wid*16 + pr*2;
    float s0 = 0.f, s1 = 0.f;
    #pragma unroll
    for (int j = 0; j < 4; ++j) {
      int k2 = ks + 8*j;                  // 0..31; attv[30],attv[31] == 0
      float a = __shfl(attv, k2);
      unsigned int w = *(const unsigned int*)(Xb + k2*512 + ((2*col0) ^ SWZ(k2)));
      s0 += a * bf2f_lo(w);
      s1 += a * bf2f_hi(w);
    }
    s0 += __shfl_xor(s0, 8);  s1 += __shfl_xor(s1, 8);
    s0 += __shfl_xor(s0, 16); s1 += __shfl_xor(s1, 16);
    s0 += __shfl_xor(s0, 32); s1 += __shfl_xor(s1, 32);
    if (lane < 8) {
      float2 o; o.x = s0; o.y = s1;
      *(float2*)(hh + (size_t)node*128 + col0) = o;
    }
  }
}

// ---------------- deterministic column reduction over nodes (on q) ------------
__global__ void reduce1_kernel(const float* __restrict__ hh, float* __restrict__ p2) {
  int b = blockIdx.x, tid = threadIdx.x;
  int d = tid & 127, half = tid >> 7;
  float s = 0.f;
  const float* base = hh + (size_t)(b*64 + half*32)*128 + d;
  #pragma unroll 4
  for (int i = 0; i < 32; ++i) s += base[(size_t)i*128];
  __shared__ float ps[256];
  ps[tid] = s; __syncthreads();
  if (tid < 128) p2[b*128 + tid] = ps[tid] + ps[tid + 128];
}

// gate: c = (mean q)@M + c3; g = sigmoid(MLP(c))
__global__ void gate_kernel(const float* __restrict__ p2,
                            const float* __restrict__ M, const float* __restrict__ c3,
                            const float* __restrict__ gw1, const float* __restrict__ gb1,
                            const float* __restrict__ gw2, const float* __restrict__ gb2,
                            const float* __restrict__ gw3, const float* __restrict__ gb3,
                            float* __restrict__ gout) {
  int tid = threadIdx.x;
  int d = tid & 127, half = tid >> 7;
  float s = 0.f;
  for (int i = 0; i < 128; ++i) s += p2[(half*128 + i)*128 + d];
  __shared__ float ps[256];
  __shared__ float cv[128], cv2[128], y1[128], y2[128];
  ps[tid] = s; __syncthreads();
  if (tid < 128) cv[tid] = (ps[tid] + ps[tid+128]) * (1.f / (float)NN);
  __syncthreads();
  if (tid < 128) {
    float a = c3[tid];
    for (int c = 0; c < 128; ++c) a += cv[c] * M[c*128 + tid];
    cv2[tid] = a;
  }
  __syncthreads();
  if (tid < 128) {
    float a = gb1[tid];
    for (int c = 0; c < 128; ++c) a += cv2[c] * gw1[c*128 + tid];
    y1[tid] = fmaxf(a, 0.f);
  }
  __syncthreads();
  if (tid < 128) {
    float a = gb2[tid];
    for (int c = 0; c < 128; ++c) a += y1[c] * gw2[c*128 + tid];
    y2[tid] = fmaxf(a, 0.f);
  }
  __syncthreads();
  if (tid < 128) {
    float a = gb3[tid];
    for (int c = 0; c < 128; ++c) a += y2[c] * gw3[c*128 + tid];
    gout[tid] = 1.f / (1.f + __expf(-a));
  }
}

// ---------------- fused (V3 + to_h + gate): out = (q@M + c3)*g, in place ------
__global__ void toh_scale_kernel(float* __restrict__ hh, const float* __restrict__ M,
                                 const float* __restrict__ c3,
                                 const float* __restrict__ gv)
{
  __shared__ float hs[16][128];
  int tid = threadIdx.x;
  size_t n0 = (size_t)blockIdx.x * 16;
  {
    int r = tid >> 4, c = (tid & 15) * 8;
    const float* src = hh + (n0 + r)*128 + c;
    *(float4*)&hs[r][c]     = *(const float4*)src;
    *(float4*)&hs[r][c + 4] = *(const float4*)(src + 4);
  }
  __syncthreads();
  int d = tid & 127, gq = tid >> 7;
  float s[8] = {0.f,0.f,0.f,0.f,0.f,0.f,0.f,0.f};
  for (int c = 0; c < 128; ++c) {
    float w = M[c*128 + d];
    #pragma unroll
    for (int r = 0; r < 8; ++r) s[r] += hs[gq*8 + r][c] * w;
  }
  float gd = gv[d];
  float cd = c3[d];
  #pragma unroll
  for (int r = 0; r < 8; ++r) hh[(n0 + gq*8 + r)*128 + d] = (s[r] + cd) * gd;
}

extern "C" void kernel_launch(void* const* d_in, const int* in_sizes, int n_in,
                              void* d_out, int out_size, void* d_ws, size_t ws_size,
                              hipStream_t stream) {
  const float* h   = (const float*)d_in[0];
  const float* e   = (const float*)d_in[1];
  const float* aw1 = (const float*)d_in[2];
  const float* ab1 = (const float*)d_in[3];
  const float* aw2 = (const float*)d_in[4];
  const float* ab2 = (const float*)d_in[5];
  const float* aw3 = (const float*)d_in[6];
  const float* ab3 = (const float*)d_in[7];
  const float* nw1 = (const float*)d_in[8];
  const float* nb1 = (const float*)d_in[9];
  const float* nw2 = (const float*)d_in[10];
  const float* nb2 = (const float*)d_in[11];
  const float* nw3 = (const float*)d_in[12];
  const float* nb3 = (const float*)d_in[13];
  const float* thw = (const float*)d_in[14];
  const float* gw1 = (const float*)d_in[15];
  const float* gb1 = (const float*)d_in[16];
  const float* gw2 = (const float*)d_in[17];
  const float* gb2 = (const float*)d_in[18];
  const float* gw3 = (const float*)d_in[19];
  const float* gb3 = (const float*)d_in[20];
  const int* edge_idx = (const int*)d_in[21];

  char* ws = (char*)d_ws;
  ushortT* WF1 = (ushortT*)(ws + 0);        // 131072 B
  ushortT* WF2 = (ushortT*)(ws + 131072);   // 65536 B
  float* bias1 = (float*)(ws + 196608);     // 1024 B
  float* bias2 = (float*)(ws + 197632);     // 1024 B
  float* p2    = (float*)(ws + 198656);     // 131072 B
  float* gout  = (float*)(ws + 329728);     // 512 B
  float* Mw    = (float*)(ws + 330240);     // 65536 B
  float* c3w   = (float*)(ws + 395776);     // 512 B
  ushortT* WVhP= (ushortT*)(ws + 396288);   // 8388608 B
  float* hh    = (float*)d_out;

  // merged prep: uwvh (2048) + pack (59) + M (129)
  prep_kernel<<<2236, 384, 0, stream>>>(h, aw1, nw1, aw2, nw2, nw3, nb3, thw,
                                        ab1, nb1, ab2, nb2,
                                        WF1, WF2, bias1, bias2,
                                        hh, WVhP, Mw, c3w);

  const int SMEM = 34304;
  hipFuncSetAttribute((const void*)edge_kernel,
                      hipFuncAttributeMaxDynamicSharedMemorySize, SMEM);
  edge_kernel<<<NN, 512, SMEM, stream>>>(e, edge_idx, WVhP, WF1, WF2,
                                         bias1, bias2, aw3, ab3, hh);

  reduce1_kernel<<<256, 256, 0, stream>>>(hh, p2);
  gate_kernel<<<1, 256, 0, stream>>>(p2, Mw, c3w, gw1, gb1, gw2, gb2, gw3, gb3, gout);
  toh_scale_kernel<<<NN/16, 256, 0, stream>>>(hh, Mw, c3w, gout);
}

// Round 20
// 279.892 us; speedup vs baseline: 3.6128x; 1.0943x over previous
//
#include <hip/hip_runtime.h>
#include <math.h>

#define NN 16384
#define KNB 30
#define NE (NN*KNB)   // 491520

typedef __attribute__((ext_vector_type(8))) __bf16 bf16x8;
typedef __attribute__((ext_vector_type(4))) float f32x4;
typedef unsigned short ushortT;
typedef __attribute__((ext_vector_type(8))) unsigned short ushort8v;

#define SWZ(r) (((r)&7)<<4)

__device__ __forceinline__ ushortT f2bf(float x){
  __bf16 b = (__bf16)x;
  union { __bf16 b; ushortT u; } v; v.b = b; return v.u;
}
__device__ __forceinline__ float bf2f(ushortT u){
  union { unsigned int u32; float f; } v; v.u32 = ((unsigned int)u) << 16;
  return v.f;
}
__device__ __forceinline__ float bf2f_lo(unsigned int w){
  union { unsigned int u32; float f; } v; v.u32 = w << 16; return v.f;
}
__device__ __forceinline__ float bf2f_hi(unsigned int w){
  union { unsigned int u32; float f; } v; v.u32 = w & 0xffff0000u; return v.f;
}
// A&S 7.1.25 erf (3-term, |err| <= 2.5e-5) — ~100x below bf16 quantization of
// the stored activation; exact-GELU compatible at harness tolerance.
__device__ __forceinline__ float gelu_f(float x){
  float ax = fabsf(x) * 0.7071067811865476f;
  float t = 1.0f / (1.0f + 0.47047f * ax);
  float poly = t*(0.3480242f + t*(-0.0958798f + t*0.7478556f));
  float er = 1.0f - poly * __expf(-ax*ax);
  er = copysignf(er, x);
  return 0.5f * x * (1.0f + er);
}

// ---------------- pack kernel --------------------------------------------------
// cascade blocks 0..73 (u = b*256+tid):
//   u < 8192   : WF1 fragments (edge GEMM1 weights)   [as r17]
//   u < 12288  : WF2 fragments (edge GEMM2 weights)   [as r17]
//   u < 18432  : WB fragments (uwvh GEMM weights, 24 tiles x 4 kt):
//                tile tt: cols tt*16+m from  tt<8: aw1[k][...]   (U part)
//                                            tt<16: aw1[256+k][.] (att-hj)
//                                            else : nw1[128+k][.] (node-hj)
//   u < 18688  : bias1 ; u < 18944 : bias2
// blocks 74..202: M = nw3@thw, c3 = nb3@thw
__global__ void pack_kernel(const float* __restrict__ aw1, const float* __restrict__ nw1,
                            const float* __restrict__ aw2, const float* __restrict__ nw2,
                            const float* __restrict__ nw3, const float* __restrict__ nb3,
                            const float* __restrict__ thw,
                            const float* __restrict__ ab1, const float* __restrict__ nb1,
                            const float* __restrict__ ab2, const float* __restrict__ nb2,
                            ushortT* __restrict__ WF1, ushortT* __restrict__ WF2,
                            ushortT* __restrict__ WB,
                            float* __restrict__ bias1, float* __restrict__ bias2,
                            float* __restrict__ M, float* __restrict__ c3)
{
  __shared__ float sbuf[128];
  int tid = threadIdx.x;
  int b = blockIdx.x;

  if (b < 74) {
    int u = b * 256 + tid;
    if (u < 8192) {
      int lane = u & 63, tile = u >> 6;
      int half = tile >> 6, nt = (tile >> 3) & 7, kt = tile & 7;
      int mrow = lane & 15, krow = lane >> 4;
      int n = half*128 + nt*16 + mrow, k0 = kt*32 + krow*8;
      ushort8v o;
      #pragma unroll
      for (int j = 0; j < 8; ++j) {
        int k = k0 + j;
        float v = (half == 0) ? aw1[(128 + k)*128 + n] : nw1[k*128 + (n - 128)];
        o[j] = f2bf(v);
      }
      *(ushort8v*)(WF1 + (size_t)u*8) = o;
      return;
    }
    u -= 8192;
    if (u < 4096) {
      int lane = u & 63, tile = u >> 6;
      int half = tile >> 5, nt = (tile >> 2) & 7, kt = tile & 3;
      int mrow = lane & 15, krow = lane >> 4;
      int n = half*128 + nt*16 + mrow, k0 = kt*32 + krow*8;
      ushort8v o;
      #pragma unroll
      for (int j = 0; j < 8; ++j) {
        int k = k0 + j;
        float v = (half == 0) ? aw2[k*128 + n] : nw2[k*128 + (n - 128)];
        o[j] = f2bf(v);
      }
      *(ushort8v*)(WF2 + (size_t)u*8) = o;
      return;
    }
    u -= 4096;
    if (u < 6144) {
      int lane = u & 63, tile = u >> 6;       // tile 0..95
      int tt = tile >> 2, kt = tile & 3;      // tt 0..23
      int mrow = lane & 15, krow = lane >> 4;
      int n = (tt & 7)*16 + mrow, k0 = kt*32 + krow*8;
      ushort8v o;
      #pragma unroll
      for (int j = 0; j < 8; ++j) {
        int k = k0 + j;
        float v = (tt < 8)  ? aw1[k*128 + n]
                : (tt < 16) ? aw1[(256 + k)*128 + n]
                            : nw1[(128 + k)*128 + n];
        o[j] = f2bf(v);
      }
      *(ushort8v*)(WB + (size_t)u*8) = o;
      return;
    }
    u -= 6144;
    if (u < 256) { bias1[u] = (u < 128) ? ab1[u] : nb1[u - 128]; return; }
    u -= 256;
    if (u < 256) { bias2[u] = (u < 128) ? ab2[u] : nb2[u - 128]; return; }
    return;
  }
  {
    // ---- M / c3: 129 blocks, 128 threads used ----
    if (tid >= 128) return;
    int bb = b - 74;
    int d = tid;
    sbuf[d] = (bb < 128) ? nw3[bb*128 + d] : nb3[d];
    __syncthreads();
    float s = 0.f;
    for (int n = 0; n < 128; ++n) s += sbuf[n] * thw[n*128 + d];
    if (bb < 128) M[bb*128 + d] = s;
    else c3[d] = s;
  }
}

// ---------------- uwvh via MFMA: [U | WVh_att | WVh_node] = h @ WB -------------
// 32 nodes/block, 512 threads, 8 waves x 3 col-tiles (N=384), K=128, acc[2][3].
// U cols (t<8) stored f32 into hh; hj cols stored bf16 interleaved into WVhP.
__global__ __launch_bounds__(512, 8) void uwvh_kernel(
    const float* __restrict__ h, const ushortT* __restrict__ WB,
    float* __restrict__ U, ushortT* __restrict__ WVhP)
{
  __shared__ char Ah[8192];                 // [32 rows][256B] swizzled bf16

  const int tid  = threadIdx.x;
  const int lane = tid & 63;
  const int wid  = tid >> 6;
  const int mrow = lane & 15, krow = lane >> 4;
  const size_t n0 = (size_t)blockIdx.x * 32;

  // stage h (32 rows x 128 bf16)
  {
    int r = tid >> 4, c8 = tid & 15;
    const float* src = h + (n0 + r)*128 + c8*8;
    float4 v0 = *(const float4*)src;
    float4 v1 = *(const float4*)(src + 4);
    ushort8v u;
    u[0]=f2bf(v0.x); u[1]=f2bf(v0.y); u[2]=f2bf(v0.z); u[3]=f2bf(v0.w);
    u[4]=f2bf(v1.x); u[5]=f2bf(v1.y); u[6]=f2bf(v1.z); u[7]=f2bf(v1.w);
    *(ushort8v*)(Ah + r*256 + ((c8*16) ^ SWZ(r))) = u;
  }
  __syncthreads();

  f32x4 acc[2][3];
  #pragma unroll
  for (int mt = 0; mt < 2; ++mt)
    #pragma unroll
    for (int j = 0; j < 3; ++j) acc[mt][j] = (f32x4){0.f,0.f,0.f,0.f};

  #pragma unroll
  for (int kt = 0; kt < 4; ++kt) {
    int koff = kt*64 + krow*16;
    bf16x8 a0 = *(const bf16x8*)(Ah + mrow*256 + (koff ^ SWZ(mrow)));
    bf16x8 a1 = *(const bf16x8*)(Ah + (16 + mrow)*256 + (koff ^ SWZ(16 + mrow)));
    #pragma unroll
    for (int j = 0; j < 3; ++j) {
      bf16x8 bfr = *(const bf16x8*)(WB + ((size_t)((wid*3 + j)*4 + kt))*512 + lane*8);
      acc[0][j] = __builtin_amdgcn_mfma_f32_16x16x32_bf16(a0, bfr, acc[0][j], 0, 0, 0);
      acc[1][j] = __builtin_amdgcn_mfma_f32_16x16x32_bf16(a1, bfr, acc[1][j], 0, 0, 0);
    }
  }

  // epilogue: t = wid*3 + j (wave-uniform)
  #pragma unroll
  for (int j = 0; j < 3; ++j) {
    int t = wid*3 + j;
    #pragma unroll
    for (int mt = 0; mt < 2; ++mt)
      #pragma unroll
      for (int rr = 0; rr < 4; ++rr) {
        int row = mt*16 + krow*4 + rr;
        size_t node = n0 + row;
        float v = acc[mt][j][rr];
        if (t < 8) {
          U[node*128 + t*16 + mrow] = v;
        } else if (t < 16) {
          WVhP[node*256 + 2*((t - 8)*16 + mrow)] = f2bf(v);
        } else {
          WVhP[node*256 + 2*((t - 16)*16 + mrow) + 1] = f2bf(v);
        }
      }
  }
}

// ---------------- fused edge pipeline (r13/r17 form, unchanged) ----------------
__global__ __launch_bounds__(512, 8) void edge_kernel(
    const float* __restrict__ e,
    const int* __restrict__ edge_idx,
    const ushortT* __restrict__ WVhP,
    const ushortT* __restrict__ WF1, const ushortT* __restrict__ WF2,
    const float* __restrict__ bias1, const float* __restrict__ bias2,
    const float* __restrict__ aw3, const float* __restrict__ ab3,
    float* __restrict__ hh)
{
  extern __shared__ char smem[];
  char*  Xb   = smem;                       // [32][512B] swizzled bf16 (16384 B)
  char*  Yb   = smem + 16384;               // [32][512B] swizzled bf16 (16384 B)
  float* lgp  = (float*)(smem + 32768);     // [8][32] logits partials
  float* Ubs  = (float*)(smem + 33792);     // [128]

  const int tid  = threadIdx.x;
  const int lane = tid & 63;
  const int wid  = tid >> 6;
  const int node = blockIdx.x;
  const long e0 = (long)node * KNB;

  const int mrow = lane & 15, krow = lane >> 4;
  const int ca = wid*16 + mrow;            // this thread's att col (0..127)

  // U value for this thread's column (precomputed into hh row)
  float uval = 0.f;
  if (tid < 128) uval = hh[(size_t)node*128 + tid];

  // ---- Phase 0a: stage e -> bf16 Xb cols 0..127; rows 30/31 zeroed ----
  {
    int r = tid >> 4, c8 = tid & 15;       // 32 rows x 16 groups = 512
    ushort8v u = {0,0,0,0,0,0,0,0};
    if (r < KNB) {
      const float* src = e + ((size_t)(e0 + r))*128 + c8*8;
      float4 v0 = *(const float4*)src;
      float4 v1 = *(const float4*)(src + 4);
      u[0]=f2bf(v0.x); u[1]=f2bf(v0.y); u[2]=f2bf(v0.z); u[3]=f2bf(v0.w);
      u[4]=f2bf(v1.x); u[5]=f2bf(v1.y); u[6]=f2bf(v1.z); u[7]=f2bf(v1.w);
    }
    *(ushort8v*)(Xb + r*512 + ((c8*16) ^ SWZ(r))) = u;
  }

  // ---- Phase 0b: issue WVh gathers — 1 interleaved dword per owned row ----
  unsigned int wv[8];
  #pragma unroll
  for (int g = 0; g < 8; ++g) {
    int row_ = (g >> 2)*16 + krow*4 + (g & 3);
    wv[g] = 0u;
    if (row_ < KNB) {
      int dst = edge_idx[NE + e0 + row_];
      wv[g] = ((const unsigned int*)(WVhP + (size_t)dst*256))[ca];
    }
  }
  if (tid < 128) Ubs[tid] = uval;
  // barrier 1: LDS drained; WVh gathers stay in flight through GEMM1
  asm volatile("s_waitcnt lgkmcnt(0)" ::: "memory");
  __builtin_amdgcn_s_barrier();

  // per-thread column constants; aw3 pre-scaled by 1/sqrt(DH)
  const float b1a = bias1[ca],       b1n = bias1[128 + ca];
  const float b2a = bias2[ca],       b2n = bias2[128 + ca];
  const float aw3c = aw3[ca] * 0.08838834764831845f;

  f32x4 acc[2][2];
  #pragma unroll
  for (int mt = 0; mt < 2; ++mt)
    #pragma unroll
    for (int j = 0; j < 2; ++j) acc[mt][j] = (f32x4){0.f,0.f,0.f,0.f};

  // ---- GEMM1: e[32x128] @ WF1 -> all 32 rows x (att tile wid, node tile wid) --
  #pragma unroll
  for (int kt = 0; kt < 4; ++kt) {
    int koff = kt*64 + krow*16;
    bf16x8 a0 = *(const bf16x8*)(Xb + mrow*512 + (koff ^ SWZ(mrow)));
    bf16x8 a1 = *(const bf16x8*)(Xb + (16 + mrow)*512 + (koff ^ SWZ(16 + mrow)));
    bf16x8 ba = *(const bf16x8*)(WF1 + ((size_t)(wid*8 + kt))*512 + lane*8);
    bf16x8 bn = *(const bf16x8*)(WF1 + ((size_t)((8 + wid)*8 + kt))*512 + lane*8);
    acc[0][0] = __builtin_amdgcn_mfma_f32_16x16x32_bf16(a0, ba, acc[0][0], 0, 0, 0);
    acc[1][0] = __builtin_amdgcn_mfma_f32_16x16x32_bf16(a1, ba, acc[1][0], 0, 0, 0);
    acc[0][1] = __builtin_amdgcn_mfma_f32_16x16x32_bf16(a0, bn, acc[0][1], 0, 0, 0);
    acc[1][1] = __builtin_amdgcn_mfma_f32_16x16x32_bf16(a1, bn, acc[1][1], 0, 0, 0);
  }

  // epilogue 1 (no barrier: acc wave-private, output -> Yb)
  {
    const float b1u = b1a + Ubs[ca];
    #pragma unroll
    for (int mt = 0; mt < 2; ++mt)
      #pragma unroll
      for (int rr = 0; rr < 4; ++rr) {
        int row_ = mt*16 + krow*4 + rr;
        int g = mt*4 + rr;
        char* yrow = Yb + row_*512;
        int sw = SWZ(row_);
        float x = fmaxf(acc[mt][0][rr] + b1u + bf2f_lo(wv[g]), 0.f);
        *(ushortT*)(yrow + ((2*ca) ^ sw)) = f2bf(x);
        float y = gelu_f(acc[mt][1][rr] + b1n + bf2f_hi(wv[g]));
        *(ushortT*)(yrow + ((256 + 2*ca) ^ sw)) = f2bf(y);
      }
  }
  __syncthreads();   // barrier 2: Yb (W1|V1) visible to all waves

  // ---- GEMM2: W2 = W1@aw2 (att), V2pre = V1@nw2 (node), A from Yb ----
  #pragma unroll
  for (int mt = 0; mt < 2; ++mt)
    #pragma unroll
    for (int j = 0; j < 2; ++j) acc[mt][j] = (f32x4){0.f,0.f,0.f,0.f};
  #pragma unroll
  for (int kt = 0; kt < 4; ++kt) {
    int koff = kt*64 + krow*16;
    bf16x8 aw0 = *(const bf16x8*)(Yb + mrow*512 + (koff ^ SWZ(mrow)));
    bf16x8 aw1v = *(const bf16x8*)(Yb + (16 + mrow)*512 + (koff ^ SWZ(16 + mrow)));
    bf16x8 av0 = *(const bf16x8*)(Yb + mrow*512 + ((256 + koff) ^ SWZ(mrow)));
    bf16x8 av1 = *(const bf16x8*)(Yb + (16 + mrow)*512 + ((256 + koff) ^ SWZ(16 + mrow)));
    bf16x8 ba = *(const bf16x8*)(WF2 + ((size_t)(wid*4 + kt))*512 + lane*8);
    bf16x8 bn = *(const bf16x8*)(WF2 + ((size_t)((8 + wid)*4 + kt))*512 + lane*8);
    acc[0][0] = __builtin_amdgcn_mfma_f32_16x16x32_bf16(aw0, ba, acc[0][0], 0, 0, 0);
    acc[1][0] = __builtin_amdgcn_mfma_f32_16x16x32_bf16(aw1v, ba, acc[1][0], 0, 0, 0);
    acc[0][1] = __builtin_amdgcn_mfma_f32_16x16x32_bf16(av0, bn, acc[0][1], 0, 0, 0);
    acc[1][1] = __builtin_amdgcn_mfma_f32_16x16x32_bf16(av1, bn, acc[1][1], 0, 0, 0);
  }

  // epilogue 2 (no barrier): logits partial from in-reg W2, V2 -> Xb left half
  {
    #pragma unroll
    for (int mt = 0; mt < 2; ++mt)
      #pragma unroll
      for (int rr = 0; rr < 4; ++rr) {
        int row_ = mt*16 + krow*4 + rr;
        int sw = SWZ(row_);
        float lsum = fmaxf(acc[mt][0][rr] + b2a, 0.f) * aw3c;
        lsum += __shfl_xor(lsum, 1);
        lsum += __shfl_xor(lsum, 2);
        lsum += __shfl_xor(lsum, 4);
        lsum += __shfl_xor(lsum, 8);
        if (mrow == 0) lgp[wid*32 + row_] = lsum;
        float y = gelu_f(acc[mt][1][rr] + b2n);
        *(ushortT*)(Xb + row_*512 + ((2*ca) ^ sw)) = f2bf(y);
      }
  }
  __syncthreads();   // barrier 3: V2 (Xb) + lgp visible

  // ---- softmax (shift-invariant, 32-lane reduce) + q = att@V2 (paired) ----
  {
    float x = -INFINITY;
    if (lane < KNB) {
      x = lgp[lane];
      #pragma unroll
      for (int w = 1; w < 8; ++w) x += lgp[w*32 + lane];
    }
    float m = x;
    #pragma unroll
    for (int off = 16; off >= 1; off >>= 1) m = fmaxf(m, __shfl_xor(m, off));
    float p = (lane < KNB) ? __expf(x - m) : 0.f;
    float ssum = p;
    #pragma unroll
    for (int off = 16; off >= 1; off >>= 1) ssum += __shfl_xor(ssum, off);
    float attv = p / ssum;   // lanes 30,31 -> 0 (rows 30/31 finite, weight 0)

    int pr = lane & 7, ks = lane >> 3;
    int col0 = wid*16 + pr*2;
    float s0 = 0.f, s1 = 0.f;
    #pragma unroll
    for (int j = 0; j < 4; ++j) {
      int k2 = ks + 8*j;                  // 0..31; attv[30],attv[31] == 0
      float a = __shfl(attv, k2);
      unsigned int w = *(const unsigned int*)(Xb + k2*512 + ((2*col0) ^ SWZ(k2)));
      s0 += a * bf2f_lo(w);
      s1 += a * bf2f_hi(w);
    }
    s0 += __shfl_xor(s0, 8);  s1 += __shfl_xor(s1, 8);
    s0 += __shfl_xor(s0, 16); s1 += __shfl_xor(s1, 16);
    s0 += __shfl_xor(s0, 32); s1 += __shfl_xor(s1, 32);
    if (lane < 8) {
      float2 o; o.x = s0; o.y = s1;
      *(float2*)(hh + (size_t)node*128 + col0) = o;
    }
  }
}

// ---------------- deterministic column reduction over nodes (on q) ------------
__global__ void reduce1_kernel(const float* __restrict__ hh, float* __restrict__ p2) {
  int b = blockIdx.x, tid = threadIdx.x;
  int d = tid & 127, half = tid >> 7;
  float s = 0.f;
  const float* base = hh + (size_t)(b*64 + half*32)*128 + d;
  #pragma unroll 4
  for (int i = 0; i < 32; ++i) s += base[(size_t)i*128];
  __shared__ float ps[256];
  ps[tid] = s; __syncthreads();
  if (tid < 128) p2[b*128 + tid] = ps[tid] + ps[tid + 128];
}

// gate: c = (mean q)@M + c3; g = sigmoid(MLP(c))
__global__ void gate_kernel(const float* __restrict__ p2,
                            const float* __restrict__ M, const float* __restrict__ c3,
                            const float* __restrict__ gw1, const float* __restrict__ gb1,
                            const float* __restrict__ gw2, const float* __restrict__ gb2,
                            const float* __restrict__ gw3, const float* __restrict__ gb3,
                            float* __restrict__ gout) {
  int tid = threadIdx.x;
  int d = tid & 127, half = tid >> 7;
  float s = 0.f;
  for (int i = 0; i < 128; ++i) s += p2[(half*128 + i)*128 + d];
  __shared__ float ps[256];
  __shared__ float cv[128], cv2[128], y1[128], y2[128];
  ps[tid] = s; __syncthreads();
  if (tid < 128) cv[tid] = (ps[tid] + ps[tid+128]) * (1.f / (float)NN);
  __syncthreads();
  if (tid < 128) {
    float a = c3[tid];
    for (int c = 0; c < 128; ++c) a += cv[c] * M[c*128 + tid];
    cv2[tid] = a;
  }
  __syncthreads();
  if (tid < 128) {
    float a = gb1[tid];
    for (int c = 0; c < 128; ++c) a += cv2[c] * gw1[c*128 + tid];
    y1[tid] = fmaxf(a, 0.f);
  }
  __syncthreads();
  if (tid < 128) {
    float a = gb2[tid];
    for (int c = 0; c < 128; ++c) a += y1[c] * gw2[c*128 + tid];
    y2[tid] = fmaxf(a, 0.f);
  }
  __syncthreads();
  if (tid < 128) {
    float a = gb3[tid];
    for (int c = 0; c < 128; ++c) a += y2[c] * gw3[c*128 + tid];
    gout[tid] = 1.f / (1.f + __expf(-a));
  }
}

// ---------------- fused (V3 + to_h + gate): out = (q@M + c3)*g, in place ------
__global__ void toh_scale_kernel(float* __restrict__ hh, const float* __restrict__ M,
                                 const float* __restrict__ c3,
                                 const float* __restrict__ gv)
{
  __shared__ float hs[16][128];
  int tid = threadIdx.x;
  size_t n0 = (size_t)blockIdx.x * 16;
  {
    int r = tid >> 4, c = (tid & 15) * 8;
    const float* src = hh + (n0 + r)*128 + c;
    *(float4*)&hs[r][c]     = *(const float4*)src;
    *(float4*)&hs[r][c + 4] = *(const float4*)(src + 4);
  }
  __syncthreads();
  int d = tid & 127, gq = tid >> 7;
  float s[8] = {0.f,0.f,0.f,0.f,0.f,0.f,0.f,0.f};
  for (int c = 0; c < 128; ++c) {
    float w = M[c*128 + d];
    #pragma unroll
    for (int r = 0; r < 8; ++r) s[r] += hs[gq*8 + r][c] * w;
  }
  float gd = gv[d];
  float cd = c3[d];
  #pragma unroll
  for (int r = 0; r < 8; ++r) hh[(n0 + gq*8 + r)*128 + d] = (s[r] + cd) * gd;
}

extern "C" void kernel_launch(void* const* d_in, const int* in_sizes, int n_in,
                              void* d_out, int out_size, void* d_ws, size_t ws_size,
                              hipStream_t stream) {
  const float* h   = (const float*)d_in[0];
  const float* e   = (const float*)d_in[1];
  const float* aw1 = (const float*)d_in[2];
  const float* ab1 = (const float*)d_in[3];
  const float* aw2 = (const float*)d_in[4];
  const float* ab2 = (const float*)d_in[5];
  const float* aw3 = (const float*)d_in[6];
  const float* ab3 = (const float*)d_in[7];
  const float* nw1 = (const float*)d_in[8];
  const float* nb1 = (const float*)d_in[9];
  const float* nw2 = (const float*)d_in[10];
  const float* nb2 = (const float*)d_in[11];
  const float* nw3 = (const float*)d_in[12];
  const float* nb3 = (const float*)d_in[13];
  const float* thw = (const float*)d_in[14];
  const float* gw1 = (const float*)d_in[15];
  const float* gb1 = (const float*)d_in[16];
  const float* gw2 = (const float*)d_in[17];
  const float* gb2 = (const float*)d_in[18];
  const float* gw3 = (const float*)d_in[19];
  const float* gb3 = (const float*)d_in[20];
  const int* edge_idx = (const int*)d_in[21];

  char* ws = (char*)d_ws;
  ushortT* WF1 = (ushortT*)(ws + 0);        // 131072 B
  ushortT* WF2 = (ushortT*)(ws + 131072);   // 65536 B
  float* bias1 = (float*)(ws + 196608);     // 1024 B
  float* bias2 = (float*)(ws + 197632);     // 1024 B
  float* p2    = (float*)(ws + 198656);     // 131072 B
  float* gout  = (float*)(ws + 329728);     // 512 B
  float* Mw    = (float*)(ws + 330240);     // 65536 B
  float* c3w   = (float*)(ws + 395776);     // 512 B
  ushortT* WVhP= (ushortT*)(ws + 396288);   // 8388608 B
  ushortT* WB  = (ushortT*)(ws + 8784896);  // 98304 B
  float* hh    = (float*)d_out;

  // 1) pack: edge weights + uwvh weights + bias + M/c3
  pack_kernel<<<203, 256, 0, stream>>>(aw1, nw1, aw2, nw2, nw3, nb3, thw,
                                       ab1, nb1, ab2, nb2,
                                       WF1, WF2, WB, bias1, bias2, Mw, c3w);

  // 2) uwvh via MFMA: U (f32 -> hh) + WVhP (bf16)
  uwvh_kernel<<<NN/32, 512, 0, stream>>>(h, WB, hh, WVhP);

  // 3) edge pipeline (r13/r17 structure, unchanged)
  const int SMEM = 34304;
  hipFuncSetAttribute((const void*)edge_kernel,
                      hipFuncAttributeMaxDynamicSharedMemorySize, SMEM);
  edge_kernel<<<NN, 512, SMEM, stream>>>(e, edge_idx, WVhP, WF1, WF2,
                                         bias1, bias2, aw3, ab3, hh);

  reduce1_kernel<<<256, 256, 0, stream>>>(hh, p2);
  gate_kernel<<<1, 256, 0, stream>>>(p2, Mw, c3w, gw1, gb1, gw2, gb2, gw3, gb3, gout);
  toh_scale_kernel<<<NN/16, 256, 0, stream>>>(hh, Mw, c3w, gout);
}

// Round 21
// 278.864 us; speedup vs baseline: 3.6261x; 1.0037x over previous
//
#include <hip/hip_runtime.h>
#include <math.h>

#define NN 16384
#define KNB 30
#define NE (NN*KNB)   // 491520

typedef __attribute__((ext_vector_type(8))) __bf16 bf16x8;
typedef __attribute__((ext_vector_type(4))) float f32x4;
typedef unsigned short ushortT;
typedef __attribute__((ext_vector_type(8))) unsigned short ushort8v;

#define SWZ(r) (((r)&7)<<4)

__device__ __forceinline__ ushortT f2bf(float x){
  __bf16 b = (__bf16)x;
  union { __bf16 b; ushortT u; } v; v.b = b; return v.u;
}
__device__ __forceinline__ float bf2f(ushortT u){
  union { unsigned int u32; float f; } v; v.u32 = ((unsigned int)u) << 16;
  return v.f;
}
__device__ __forceinline__ float bf2f_lo(unsigned int w){
  union { unsigned int u32; float f; } v; v.u32 = w << 16; return v.f;
}
__device__ __forceinline__ float bf2f_hi(unsigned int w){
  union { unsigned int u32; float f; } v; v.u32 = w & 0xffff0000u; return v.f;
}
// A&S 7.1.25 erf (3-term, |err| <= 2.5e-5) — ~100x below bf16 quantization of
// the stored activation; exact-GELU compatible at harness tolerance.
__device__ __forceinline__ float gelu_f(float x){
  float ax = fabsf(x) * 0.7071067811865476f;
  float t = 1.0f / (1.0f + 0.47047f * ax);
  float poly = t*(0.3480242f + t*(-0.0958798f + t*0.7478556f));
  float er = 1.0f - poly * __expf(-ax*ax);
  er = copysignf(er, x);
  return 0.5f * x * (1.0f + er);
}

// ---------------- pack kernel --------------------------------------------------
// cascade blocks 0..73 (u = b*256+tid): WF1 | WF2 | WB | bias1 | bias2
// blocks 74..202: M = nw3@thw, c3 = nb3@thw.  Block 0 also zeroes the
// reduce-gate completion counter (stream-ordered before reduce1_gate).
__global__ void pack_kernel(const float* __restrict__ aw1, const float* __restrict__ nw1,
                            const float* __restrict__ aw2, const float* __restrict__ nw2,
                            const float* __restrict__ nw3, const float* __restrict__ nb3,
                            const float* __restrict__ thw,
                            const float* __restrict__ ab1, const float* __restrict__ nb1,
                            const float* __restrict__ ab2, const float* __restrict__ nb2,
                            ushortT* __restrict__ WF1, ushortT* __restrict__ WF2,
                            ushortT* __restrict__ WB,
                            float* __restrict__ bias1, float* __restrict__ bias2,
                            float* __restrict__ M, float* __restrict__ c3,
                            unsigned int* __restrict__ cnt)
{
  __shared__ float sbuf[128];
  int tid = threadIdx.x;
  int b = blockIdx.x;

  if (b == 0 && tid == 0) *cnt = 0u;

  if (b < 74) {
    int u = b * 256 + tid;
    if (u < 8192) {
      int lane = u & 63, tile = u >> 6;
      int half = tile >> 6, nt = (tile >> 3) & 7, kt = tile & 7;
      int mrow = lane & 15, krow = lane >> 4;
      int n = half*128 + nt*16 + mrow, k0 = kt*32 + krow*8;
      ushort8v o;
      #pragma unroll
      for (int j = 0; j < 8; ++j) {
        int k = k0 + j;
        float v = (half == 0) ? aw1[(128 + k)*128 + n] : nw1[k*128 + (n - 128)];
        o[j] = f2bf(v);
      }
      *(ushort8v*)(WF1 + (size_t)u*8) = o;
      return;
    }
    u -= 8192;
    if (u < 4096) {
      int lane = u & 63, tile = u >> 6;
      int half = tile >> 5, nt = (tile >> 2) & 7, kt = tile & 3;
      int mrow = lane & 15, krow = lane >> 4;
      int n = half*128 + nt*16 + mrow, k0 = kt*32 + krow*8;
      ushort8v o;
      #pragma unroll
      for (int j = 0; j < 8; ++j) {
        int k = k0 + j;
        float v = (half == 0) ? aw2[k*128 + n] : nw2[k*128 + (n - 128)];
        o[j] = f2bf(v);
      }
      *(ushort8v*)(WF2 + (size_t)u*8) = o;
      return;
    }
    u -= 4096;
    if (u < 6144) {
      int lane = u & 63, tile = u >> 6;       // tile 0..95
      int tt = tile >> 2, kt = tile & 3;      // tt 0..23
      int mrow = lane & 15, krow = lane >> 4;
      int n = (tt & 7)*16 + mrow, k0 = kt*32 + krow*8;
      ushort8v o;
      #pragma unroll
      for (int j = 0; j < 8; ++j) {
        int k = k0 + j;
        float v = (tt < 8)  ? aw1[k*128 + n]
                : (tt < 16) ? aw1[(256 + k)*128 + n]
                            : nw1[(128 + k)*128 + n];
        o[j] = f2bf(v);
      }
      *(ushort8v*)(WB + (size_t)u*8) = o;
      return;
    }
    u -= 6144;
    if (u < 256) { bias1[u] = (u < 128) ? ab1[u] : nb1[u - 128]; return; }
    u -= 256;
    if (u < 256) { bias2[u] = (u < 128) ? ab2[u] : nb2[u - 128]; return; }
    return;
  }
  {
    // ---- M / c3: 129 blocks, 128 threads used ----
    if (tid >= 128) return;
    int bb = b - 74;
    int d = tid;
    sbuf[d] = (bb < 128) ? nw3[bb*128 + d] : nb3[d];
    __syncthreads();
    float s = 0.f;
    for (int n = 0; n < 128; ++n) s += sbuf[n] * thw[n*128 + d];
    if (bb < 128) M[bb*128 + d] = s;
    else c3[d] = s;
  }
}

// ---------------- uwvh via MFMA: [U | WVh_att | WVh_node] = h @ WB -------------
// 32 nodes/block, 512 threads, 8 waves x 3 col-tiles (N=384), K=128, acc[2][3].
__global__ __launch_bounds__(512, 8) void uwvh_kernel(
    const float* __restrict__ h, const ushortT* __restrict__ WB,
    float* __restrict__ U, ushortT* __restrict__ WVhP)
{
  __shared__ char Ah[8192];                 // [32 rows][256B] swizzled bf16

  const int tid  = threadIdx.x;
  const int lane = tid & 63;
  const int wid  = tid >> 6;
  const int mrow = lane & 15, krow = lane >> 4;
  const size_t n0 = (size_t)blockIdx.x * 32;

  // stage h (32 rows x 128 bf16)
  {
    int r = tid >> 4, c8 = tid & 15;
    const float* src = h + (n0 + r)*128 + c8*8;
    float4 v0 = *(const float4*)src;
    float4 v1 = *(const float4*)(src + 4);
    ushort8v u;
    u[0]=f2bf(v0.x); u[1]=f2bf(v0.y); u[2]=f2bf(v0.z); u[3]=f2bf(v0.w);
    u[4]=f2bf(v1.x); u[5]=f2bf(v1.y); u[6]=f2bf(v1.z); u[7]=f2bf(v1.w);
    *(ushort8v*)(Ah + r*256 + ((c8*16) ^ SWZ(r))) = u;
  }
  __syncthreads();

  f32x4 acc[2][3];
  #pragma unroll
  for (int mt = 0; mt < 2; ++mt)
    #pragma unroll
    for (int j = 0; j < 3; ++j) acc[mt][j] = (f32x4){0.f,0.f,0.f,0.f};

  #pragma unroll
  for (int kt = 0; kt < 4; ++kt) {
    int koff = kt*64 + krow*16;
    bf16x8 a0 = *(const bf16x8*)(Ah + mrow*256 + (koff ^ SWZ(mrow)));
    bf16x8 a1 = *(const bf16x8*)(Ah + (16 + mrow)*256 + (koff ^ SWZ(16 + mrow)));
    #pragma unroll
    for (int j = 0; j < 3; ++j) {
      bf16x8 bfr = *(const bf16x8*)(WB + ((size_t)((wid*3 + j)*4 + kt))*512 + lane*8);
      acc[0][j] = __builtin_amdgcn_mfma_f32_16x16x32_bf16(a0, bfr, acc[0][j], 0, 0, 0);
      acc[1][j] = __builtin_amdgcn_mfma_f32_16x16x32_bf16(a1, bfr, acc[1][j], 0, 0, 0);
    }
  }

  // epilogue: t = wid*3 + j (wave-uniform)
  #pragma unroll
  for (int j = 0; j < 3; ++j) {
    int t = wid*3 + j;
    #pragma unroll
    for (int mt = 0; mt < 2; ++mt)
      #pragma unroll
      for (int rr = 0; rr < 4; ++rr) {
        int row = mt*16 + krow*4 + rr;
        size_t node = n0 + row;
        float v = acc[mt][j][rr];
        if (t < 8) {
          U[node*128 + t*16 + mrow] = v;
        } else if (t < 16) {
          WVhP[node*256 + 2*((t - 8)*16 + mrow)] = f2bf(v);
        } else {
          WVhP[node*256 + 2*((t - 16)*16 + mrow) + 1] = f2bf(v);
        }
      }
  }
}

// ---------------- fused edge pipeline (r13/r17 form, unchanged) ----------------
__global__ __launch_bounds__(512, 8) void edge_kernel(
    const float* __restrict__ e,
    const int* __restrict__ edge_idx,
    const ushortT* __restrict__ WVhP,
    const ushortT* __restrict__ WF1, const ushortT* __restrict__ WF2,
    const float* __restrict__ bias1, const float* __restrict__ bias2,
    const float* __restrict__ aw3, const float* __restrict__ ab3,
    float* __restrict__ hh)
{
  extern __shared__ char smem[];
  char*  Xb   = smem;                       // [32][512B] swizzled bf16 (16384 B)
  char*  Yb   = smem + 16384;               // [32][512B] swizzled bf16 (16384 B)
  float* lgp  = (float*)(smem + 32768);     // [8][32] logits partials
  float* Ubs  = (float*)(smem + 33792);     // [128]

  const int tid  = threadIdx.x;
  const int lane = tid & 63;
  const int wid  = tid >> 6;
  const int node = blockIdx.x;
  const long e0 = (long)node * KNB;

  const int mrow = lane & 15, krow = lane >> 4;
  const int ca = wid*16 + mrow;            // this thread's att col (0..127)

  // U value for this thread's column (precomputed into hh row)
  float uval = 0.f;
  if (tid < 128) uval = hh[(size_t)node*128 + tid];

  // ---- Phase 0a: stage e -> bf16 Xb cols 0..127; rows 30/31 zeroed ----
  {
    int r = tid >> 4, c8 = tid & 15;       // 32 rows x 16 groups = 512
    ushort8v u = {0,0,0,0,0,0,0,0};
    if (r < KNB) {
      const float* src = e + ((size_t)(e0 + r))*128 + c8*8;
      float4 v0 = *(const float4*)src;
      float4 v1 = *(const float4*)(src + 4);
      u[0]=f2bf(v0.x); u[1]=f2bf(v0.y); u[2]=f2bf(v0.z); u[3]=f2bf(v0.w);
      u[4]=f2bf(v1.x); u[5]=f2bf(v1.y); u[6]=f2bf(v1.z); u[7]=f2bf(v1.w);
    }
    *(ushort8v*)(Xb + r*512 + ((c8*16) ^ SWZ(r))) = u;
  }

  // ---- Phase 0b: issue WVh gathers — 1 interleaved dword per owned row ----
  unsigned int wv[8];
  #pragma unroll
  for (int g = 0; g < 8; ++g) {
    int row_ = (g >> 2)*16 + krow*4 + (g & 3);
    wv[g] = 0u;
    if (row_ < KNB) {
      int dst = edge_idx[NE + e0 + row_];
      wv[g] = ((const unsigned int*)(WVhP + (size_t)dst*256))[ca];
    }
  }
  if (tid < 128) Ubs[tid] = uval;
  // barrier 1: LDS drained; WVh gathers stay in flight through GEMM1
  asm volatile("s_waitcnt lgkmcnt(0)" ::: "memory");
  __builtin_amdgcn_s_barrier();

  // per-thread column constants; aw3 pre-scaled by 1/sqrt(DH)
  const float b1a = bias1[ca],       b1n = bias1[128 + ca];
  const float b2a = bias2[ca],       b2n = bias2[128 + ca];
  const float aw3c = aw3[ca] * 0.08838834764831845f;

  f32x4 acc[2][2];
  #pragma unroll
  for (int mt = 0; mt < 2; ++mt)
    #pragma unroll
    for (int j = 0; j < 2; ++j) acc[mt][j] = (f32x4){0.f,0.f,0.f,0.f};

  // ---- GEMM1: e[32x128] @ WF1 -> all 32 rows x (att tile wid, node tile wid) --
  #pragma unroll
  for (int kt = 0; kt < 4; ++kt) {
    int koff = kt*64 + krow*16;
    bf16x8 a0 = *(const bf16x8*)(Xb + mrow*512 + (koff ^ SWZ(mrow)));
    bf16x8 a1 = *(const bf16x8*)(Xb + (16 + mrow)*512 + (koff ^ SWZ(16 + mrow)));
    bf16x8 ba = *(const bf16x8*)(WF1 + ((size_t)(wid*8 + kt))*512 + lane*8);
    bf16x8 bn = *(const bf16x8*)(WF1 + ((size_t)((8 + wid)*8 + kt))*512 + lane*8);
    acc[0][0] = __builtin_amdgcn_mfma_f32_16x16x32_bf16(a0, ba, acc[0][0], 0, 0, 0);
    acc[1][0] = __builtin_amdgcn_mfma_f32_16x16x32_bf16(a1, ba, acc[1][0], 0, 0, 0);
    acc[0][1] = __builtin_amdgcn_mfma_f32_16x16x32_bf16(a0, bn, acc[0][1], 0, 0, 0);
    acc[1][1] = __builtin_amdgcn_mfma_f32_16x16x32_bf16(a1, bn, acc[1][1], 0, 0, 0);
  }

  // epilogue 1 (no barrier: acc wave-private, output -> Yb)
  {
    const float b1u = b1a + Ubs[ca];
    #pragma unroll
    for (int mt = 0; mt < 2; ++mt)
      #pragma unroll
      for (int rr = 0; rr < 4; ++rr) {
        int row_ = mt*16 + krow*4 + rr;
        int g = mt*4 + rr;
        char* yrow = Yb + row_*512;
        int sw = SWZ(row_);
        float x = fmaxf(acc[mt][0][rr] + b1u + bf2f_lo(wv[g]), 0.f);
        *(ushortT*)(yrow + ((2*ca) ^ sw)) = f2bf(x);
        float y = gelu_f(acc[mt][1][rr] + b1n + bf2f_hi(wv[g]));
        *(ushortT*)(yrow + ((256 + 2*ca) ^ sw)) = f2bf(y);
      }
  }
  __syncthreads();   // barrier 2: Yb (W1|V1) visible to all waves

  // ---- GEMM2: W2 = W1@aw2 (att), V2pre = V1@nw2 (node), A from Yb ----
  #pragma unroll
  for (int mt = 0; mt < 2; ++mt)
    #pragma unroll
    for (int j = 0; j < 2; ++j) acc[mt][j] = (f32x4){0.f,0.f,0.f,0.f};
  #pragma unroll
  for (int kt = 0; kt < 4; ++kt) {
    int koff = kt*64 + krow*16;
    bf16x8 aw0 = *(const bf16x8*)(Yb + mrow*512 + (koff ^ SWZ(mrow)));
    bf16x8 aw1v = *(const bf16x8*)(Yb + (16 + mrow)*512 + (koff ^ SWZ(16 + mrow)));
    bf16x8 av0 = *(const bf16x8*)(Yb + mrow*512 + ((256 + koff) ^ SWZ(mrow)));
    bf16x8 av1 = *(const bf16x8*)(Yb + (16 + mrow)*512 + ((256 + koff) ^ SWZ(16 + mrow)));
    bf16x8 ba = *(const bf16x8*)(WF2 + ((size_t)(wid*4 + kt))*512 + lane*8);
    bf16x8 bn = *(const bf16x8*)(WF2 + ((size_t)((8 + wid)*4 + kt))*512 + lane*8);
    acc[0][0] = __builtin_amdgcn_mfma_f32_16x16x32_bf16(aw0, ba, acc[0][0], 0, 0, 0);
    acc[1][0] = __builtin_amdgcn_mfma_f32_16x16x32_bf16(aw1v, ba, acc[1][0], 0, 0, 0);
    acc[0][1] = __builtin_amdgcn_mfma_f32_16x16x32_bf16(av0, bn, acc[0][1], 0, 0, 0);
    acc[1][1] = __builtin_amdgcn_mfma_f32_16x16x32_bf16(av1, bn, acc[1][1], 0, 0, 0);
  }

  // epilogue 2 (no barrier): logits partial from in-reg W2, V2 -> Xb left half
  {
    #pragma unroll
    for (int mt = 0; mt < 2; ++mt)
      #pragma unroll
      for (int rr = 0; rr < 4; ++rr) {
        int row_ = mt*16 + krow*4 + rr;
        int sw = SWZ(row_);
        float lsum = fmaxf(acc[mt][0][rr] + b2a, 0.f) * aw3c;
        lsum += __shfl_xor(lsum, 1);
        lsum += __shfl_xor(lsum, 2);
        lsum += __shfl_xor(lsum, 4);
        lsum += __shfl_xor(lsum, 8);
        if (mrow == 0) lgp[wid*32 + row_] = lsum;
        float y = gelu_f(acc[mt][1][rr] + b2n);
        *(ushortT*)(Xb + row_*512 + ((2*ca) ^ sw)) = f2bf(y);
      }
  }
  __syncthreads();   // barrier 3: V2 (Xb) + lgp visible

  // ---- softmax (shift-invariant, 32-lane reduce) + q = att@V2 (paired) ----
  {
    float x = -INFINITY;
    if (lane < KNB) {
      x = lgp[lane];
      #pragma unroll
      for (int w = 1; w < 8; ++w) x += lgp[w*32 + lane];
    }
    float m = x;
    #pragma unroll
    for (int off = 16; off >= 1; off >>= 1) m = fmaxf(m, __shfl_xor(m, off));
    float p = (lane < KNB) ? __expf(x - m) : 0.f;
    float ssum = p;
    #pragma unroll
    for (int off = 16; off >= 1; off >>= 1) ssum += __shfl_xor(ssum, off);
    float attv = p / ssum;   // lanes 30,31 -> 0 (rows 30/31 finite, weight 0)

    int pr = lane & 7, ks = lane >> 3;
    int col0 = wid*16 + pr*2;
    float s0 = 0.f, s1 = 0.f;
    #pragma unroll
    for (int j = 0; j < 4; ++j) {
      int k2 = ks + 8*j;                  // 0..31; attv[30],attv[31] == 0
      float a = __shfl(attv, k2);
      unsigned int w = *(const unsigned int*)(Xb + k2*512 + ((2*col0) ^ SWZ(k2)));
      s0 += a * bf2f_lo(w);
      s1 += a * bf2f_hi(w);
    }
    s0 += __shfl_xor(s0, 8);  s1 += __shfl_xor(s1, 8);
    s0 += __shfl_xor(s0, 16); s1 += __shfl_xor(s1, 16);
    s0 += __shfl_xor(s0, 32); s1 += __shfl_xor(s1, 32);
    if (lane < 8) {
      float2 o; o.x = s0; o.y = s1;
      *(float2*)(hh + (size_t)node*128 + col0) = o;
    }
  }
}

// ---------------- fused reduce + gate (last-block-done) ------------------------
// 256 blocks write p2 partials; the 256th finisher runs the gate MLP.
// Bitwise-identical math to the former reduce1 + gate pair (gate reads the
// complete deterministic p2). Counter zeroed by pack each launch.
__global__ void reduce1_gate_kernel(const float* __restrict__ hh, float* __restrict__ p2,
                                    const float* __restrict__ M, const float* __restrict__ c3,
                                    const float* __restrict__ gw1, const float* __restrict__ gb1,
                                    const float* __restrict__ gw2, const float* __restrict__ gb2,
                                    const float* __restrict__ gw3, const float* __restrict__ gb3,
                                    float* __restrict__ gout,
                                    unsigned int* __restrict__ cnt) {
  int b = blockIdx.x, tid = threadIdx.x;
  int d = tid & 127, half = tid >> 7;
  __shared__ float ps[256];
  __shared__ float cv[128], cv2[128], y1[128], y2[128];
  __shared__ int lastf;
  {
    float s = 0.f;
    const float* base = hh + (size_t)(b*64 + half*32)*128 + d;
    #pragma unroll 4
    for (int i = 0; i < 32; ++i) s += base[(size_t)i*128];
    ps[tid] = s; __syncthreads();
    if (tid < 128) p2[b*128 + tid] = ps[tid] + ps[tid + 128];
  }
  __syncthreads();
  if (tid == 0) {
    __threadfence();                        // publish this block's p2 row
    unsigned int old = atomicAdd(cnt, 1u);
    lastf = (old == 255u);
  }
  __syncthreads();
  if (!lastf) return;
  __threadfence();                          // acquire all p2 rows

  // ---- gate (identical to former gate_kernel) ----
  {
    float s = 0.f;
    for (int i = 0; i < 128; ++i) s += p2[(half*128 + i)*128 + d];
    ps[tid] = s; __syncthreads();
    if (tid < 128) cv[tid] = (ps[tid] + ps[tid+128]) * (1.f / (float)NN);
    __syncthreads();
    if (tid < 128) {
      float a = c3[tid];
      for (int c = 0; c < 128; ++c) a += cv[c] * M[c*128 + tid];
      cv2[tid] = a;
    }
    __syncthreads();
    if (tid < 128) {
      float a = gb1[tid];
      for (int c = 0; c < 128; ++c) a += cv2[c] * gw1[c*128 + tid];
      y1[tid] = fmaxf(a, 0.f);
    }
    __syncthreads();
    if (tid < 128) {
      float a = gb2[tid];
      for (int c = 0; c < 128; ++c) a += y1[c] * gw2[c*128 + tid];
      y2[tid] = fmaxf(a, 0.f);
    }
    __syncthreads();
    if (tid < 128) {
      float a = gb3[tid];
      for (int c = 0; c < 128; ++c) a += y2[c] * gw3[c*128 + tid];
      gout[tid] = 1.f / (1.f + __expf(-a));
    }
  }
}

// ---------------- fused (V3 + to_h + gate): out = (q@M + c3)*g, in place ------
__global__ void toh_scale_kernel(float* __restrict__ hh, const float* __restrict__ M,
                                 const float* __restrict__ c3,
                                 const float* __restrict__ gv)
{
  __shared__ float hs[16][128];
  int tid = threadIdx.x;
  size_t n0 = (size_t)blockIdx.x * 16;
  {
    int r = tid >> 4, c = (tid & 15) * 8;
    const float* src = hh + (n0 + r)*128 + c;
    *(float4*)&hs[r][c]     = *(const float4*)src;
    *(float4*)&hs[r][c + 4] = *(const float4*)(src + 4);
  }
  __syncthreads();
  int d = tid & 127, gq = tid >> 7;
  float s[8] = {0.f,0.f,0.f,0.f,0.f,0.f,0.f,0.f};
  for (int c = 0; c < 128; ++c) {
    float w = M[c*128 + d];
    #pragma unroll
    for (int r = 0; r < 8; ++r) s[r] += hs[gq*8 + r][c] * w;
  }
  float gd = gv[d];
  float cd = c3[d];
  #pragma unroll
  for (int r = 0; r < 8; ++r) hh[(n0 + gq*8 + r)*128 + d] = (s[r] + cd) * gd;
}

extern "C" void kernel_launch(void* const* d_in, const int* in_sizes, int n_in,
                              void* d_out, int out_size, void* d_ws, size_t ws_size,
                              hipStream_t stream) {
  const float* h   = (const float*)d_in[0];
  const float* e   = (const float*)d_in[1];
  const float* aw1 = (const float*)d_in[2];
  const float* ab1 = (const float*)d_in[3];
  const float* aw2 = (const float*)d_in[4];
  const float* ab2 = (const float*)d_in[5];
  const float* aw3 = (const float*)d_in[6];
  const float* ab3 = (const float*)d_in[7];
  const float* nw1 = (const float*)d_in[8];
  const float* nb1 = (const float*)d_in[9];
  const float* nw2 = (const float*)d_in[10];
  const float* nb2 = (const float*)d_in[11];
  const float* nw3 = (const float*)d_in[12];
  const float* nb3 = (const float*)d_in[13];
  const float* thw = (const float*)d_in[14];
  const float* gw1 = (const float*)d_in[15];
  const float* gb1 = (const float*)d_in[16];
  const float* gw2 = (const float*)d_in[17];
  const float* gb2 = (const float*)d_in[18];
  const float* gw3 = (const float*)d_in[19];
  const float* gb3 = (const float*)d_in[20];
  const int* edge_idx = (const int*)d_in[21];

  char* ws = (char*)d_ws;
  ushortT* WF1 = (ushortT*)(ws + 0);        // 131072 B
  ushortT* WF2 = (ushortT*)(ws + 131072);   // 65536 B
  float* bias1 = (float*)(ws + 196608);     // 1024 B
  float* bias2 = (float*)(ws + 197632);     // 1024 B
  float* p2    = (float*)(ws + 198656);     // 131072 B
  float* gout  = (float*)(ws + 329728);     // 512 B
  float* Mw    = (float*)(ws + 330240);     // 65536 B
  float* c3w   = (float*)(ws + 395776);     // 512 B
  ushortT* WVhP= (ushortT*)(ws + 396288);   // 8388608 B
  ushortT* WB  = (ushortT*)(ws + 8784896);  // 98304 B
  unsigned int* cnt = (unsigned int*)(ws + 8883200); // 4 B
  float* hh    = (float*)d_out;

  // 1) pack: edge weights + uwvh weights + bias + M/c3 (+ counter reset)
  pack_kernel<<<203, 256, 0, stream>>>(aw1, nw1, aw2, nw2, nw3, nb3, thw,
                                       ab1, nb1, ab2, nb2,
                                       WF1, WF2, WB, bias1, bias2, Mw, c3w, cnt);

  // 2) uwvh via MFMA: U (f32 -> hh) + WVhP (bf16)
  uwvh_kernel<<<NN/32, 512, 0, stream>>>(h, WB, hh, WVhP);

  // 3) edge pipeline (r13/r17 structure, unchanged)
  const int SMEM = 34304;
  hipFuncSetAttribute((const void*)edge_kernel,
                      hipFuncAttributeMaxDynamicSharedMemorySize, SMEM);
  edge_kernel<<<NN, 512, SMEM, stream>>>(e, edge_idx, WVhP, WF1, WF2,
                                         bias1, bias2, aw3, ab3, hh);

  // 4) reduce + gate (fused, last-block-done)
  reduce1_gate_kernel<<<256, 256, 0, stream>>>(hh, p2, Mw, c3w,
                                               gw1, gb1, gw2, gb2, gw3, gb3,
                                               gout, cnt);

  // 5) to_h + scale
  toh_scale_kernel<<<NN/16, 256, 0, stream>>>(hh, Mw, c3w, gout);
}